// Round 8
// baseline (819.828 us; speedup 1.0000x reference)
//
#include <hip/hip_runtime.h>
#include <hip/hip_cooperative_groups.h>

namespace cg = cooperative_groups;

// ---------------------------------------------------------------------------
// GGNN message passing, MI355X/gfx950.  Round 17 = R16 + two changes:
//   - agg_gru v6: v5's LDS-both-operands math + R13's parity double-buffer
//     staging for BOTH operands, BK=64.  Per step: issue next global loads
//     -> ds_write current -> ONE barrier -> MFMA (LDS-only operands).
//     8 A-steps (Sd 2x8KB, Wd 2x16KB) + 16 B-steps (Wg 16KB slices in Wd),
//     h tile staged once (Hbt over Sd), hv from LDS, Outs overlay epilogue.
//     LDS exactly 64KB.
//   - csr_build: hist+scan+top+finalize+fill fused cooperatively (1024x256,
//     4 grid.syncs).  All phases are throughput-parallel (atomics/scans) --
//     unlike R14's failure, NO latency-chain phase is throttled; gather
//     stays a separate full-parallelism launch.
// Lessons: no gather-into-GEMM fusion (R6); no K-merging (R7); LDS-staged
// coalesced out stores (R5); (dst,type) CSR (R6/R9); watch WRITE_SIZE for
// spill (R12); weights must be LDS-staged (R16); no co-op fusion of
// latency-bound phases (R14); wave-per-node gather (R15).
// ---------------------------------------------------------------------------

typedef __attribute__((ext_vector_type(8))) short short8;
typedef __attribute__((ext_vector_type(4))) float floatx4;

#define HID 128
#define NTY 4

__device__ __forceinline__ unsigned short f2bf(float f) {
    unsigned int u = __float_as_uint(f);
    unsigned int r = (u + 0x7fffu + ((u >> 16) & 1u)) >> 16;  // RNE
    return (unsigned short)r;
}
__device__ __forceinline__ float bf2f(unsigned int lo16) {
    return __uint_as_float(lo16 << 16);
}
__device__ __forceinline__ float frcp(float x) { return __builtin_amdgcn_rcpf(x); }

// ---- prep: cvt_h | pack_wcat | pack_wgru | bias4 (deg4 zero moved out) ----

__global__ void prep_kernel(const float* __restrict__ h, unsigned short* __restrict__ hbf,
                            const float* __restrict__ W, unsigned short* __restrict__ Wc,
                            const float* __restrict__ w_ih, const float* __restrict__ w_hh,
                            unsigned short* __restrict__ Wg, float* __restrict__ bias4,
                            const float* __restrict__ b_ih, const float* __restrict__ b_hh,
                            int total4, int nb_cvt) {
    int b = blockIdx.x, tt = threadIdx.x;
    if (b < nb_cvt) {
        int i = b * 256 + tt;
        if (i < total4) {
            float4 v = ((const float4*)h)[i];
            uint2 o;
            o.x = (unsigned int)f2bf(v.x) | ((unsigned int)f2bf(v.y) << 16);
            o.y = (unsigned int)f2bf(v.z) | ((unsigned int)f2bf(v.w) << 16);
            ((uint2*)hbf)[i] = o;
        }
    } else if (b < nb_cvt + 256) {
        // Wcat[j][t*128+k] = edge_W[t][j][k]  (128 x 512)
        int idx = (b - nb_cvt) * 256 + tt;
        int j = idx >> 9, rem = idx & 511;
        int t = rem >> 7, k = rem & 127;
        Wc[idx] = f2bf(W[(t * HID + j) * HID + k]);
    } else if (b < nb_cvt + 768) {
        // Wg[512][256]: rows 4j+{0,1,2,3} = r|z|i_n|h_n; cols 0-127 agg, 128-255 h
        int idx = (b - nb_cvt - 256) * 256 + tt;
        int row = idx >> 8, k = idx & 255;
        int j = row >> 2, g = row & 3;
        float v = 0.0f;
        if (g == 0) v = (k < 128) ? w_ih[j * 128 + k]         : w_hh[j * 128 + (k - 128)];
        else if (g == 1) v = (k < 128) ? w_ih[(128 + j) * 128 + k] : w_hh[(128 + j) * 128 + (k - 128)];
        else if (g == 2) v = (k < 128) ? w_ih[(256 + j) * 128 + k] : 0.0f;
        else             v = (k < 128) ? 0.0f : w_hh[(256 + j) * 128 + (k - 128)];
        Wg[idx] = f2bf(v);
    } else {
        if (tt < 128) {
            float4 v;
            v.x = b_ih[tt] + b_hh[tt];
            v.y = b_ih[128 + tt] + b_hh[128 + tt];
            v.z = b_ih[256 + tt];
            v.w = b_hh[256 + tt];
            ((float4*)bias4)[tt] = v;
        }
    }
}

// ---- csr_build: zero|hist|scan|top|finalize|fill, one cooperative launch --

struct CsrArgs {
    const int* src; const int* dst; const int* ety;
    int* deg4; int* rowptr4; int* cursor4; int* blocksum; int* blockoff; int* csr;
    int E, N4;
};

__global__ __launch_bounds__(256, 4) void csr_build(CsrArgs a) {
    cg::grid_group grid = cg::this_grid();
    __shared__ int s[256];
    const int t = threadIdx.x;
    const int gtid = blockIdx.x * 256 + t;
    const int nth = gridDim.x * 256;

    // P0: zero deg4
    for (int i = gtid; i < a.N4; i += nth) a.deg4[i] = 0;
    grid.sync();

    // P1: histogram
    for (int e = gtid; e < a.E; e += nth)
        atomicAdd(&a.deg4[a.dst[e] * 4 + a.ety[e]], 1);
    grid.sync();

    // P2: per-1024-chunk exclusive scans
    const int nbscan = (a.N4 + 1023) >> 10;
    for (int vb = blockIdx.x; vb < nbscan; vb += gridDim.x) {
        int base = vb * 1024 + t * 4;
        int v0 = 0, v1 = 0, v2 = 0, v3 = 0;
        if (base + 3 < a.N4) {
            v0 = a.deg4[base]; v1 = a.deg4[base + 1]; v2 = a.deg4[base + 2]; v3 = a.deg4[base + 3];
        } else {
            if (base < a.N4) v0 = a.deg4[base];
            if (base + 1 < a.N4) v1 = a.deg4[base + 1];
            if (base + 2 < a.N4) v2 = a.deg4[base + 2];
        }
        int sum = v0 + v1 + v2 + v3;
        s[t] = sum;
        __syncthreads();
#pragma unroll
        for (int off = 1; off < 256; off <<= 1) {
            int x = (t >= off) ? s[t - off] : 0;
            __syncthreads();
            s[t] += x;
            __syncthreads();
        }
        int ex = s[t] - sum;
        if (base < a.N4) a.rowptr4[base] = ex;
        if (base + 1 < a.N4) a.rowptr4[base + 1] = ex + v0;
        if (base + 2 < a.N4) a.rowptr4[base + 2] = ex + v0 + v1;
        if (base + 3 < a.N4) a.rowptr4[base + 3] = ex + v0 + v1 + v2;
        if (t == 255) a.blocksum[vb] = s[255];
        __syncthreads();
    }
    grid.sync();

    // P3: top scan (block 0)
    if (blockIdx.x == 0) {
        int v = (t < nbscan) ? a.blocksum[t] : 0;
        s[t] = v;
        __syncthreads();
#pragma unroll
        for (int off = 1; off < 256; off <<= 1) {
            int x = (t >= off) ? s[t - off] : 0;
            __syncthreads();
            s[t] += x;
            __syncthreads();
        }
        if (t < nbscan) a.blockoff[t] = s[t] - v;
    }
    grid.sync();

    // P4: finalize rowptr + cursor + sentinel
    for (int i = gtid; i < a.N4; i += nth) {
        int r = a.rowptr4[i] + a.blockoff[i >> 10];
        a.rowptr4[i] = r;
        a.cursor4[i] = r;
    }
    if (gtid == 0) a.rowptr4[a.N4] = a.E;
    grid.sync();

    // P5: fill CSR
    for (int e = gtid; e < a.E; e += nth) {
        int pos = atomicAdd(&a.cursor4[a.dst[e] * 4 + a.ety[e]], 1);
        a.csr[pos] = a.src[e];
    }
}

// ---- gather_s v4 (R13/R16, measured-best): flat MLP-8 + snapshots ---------

__global__ void gather_s_kernel(const int* __restrict__ rowptr4, const int* __restrict__ csr,
                                const unsigned int* __restrict__ hbu,
                                float4* __restrict__ cnt4, unsigned int* __restrict__ Su, int N) {
    int w = blockIdx.x * (blockDim.x >> 6) + (threadIdx.x >> 6);
    if (w >= N) return;
    int lane = threadIdx.x & 63;
    int b0 = __builtin_amdgcn_readfirstlane(rowptr4[w * 4]);
    int b1 = __builtin_amdgcn_readfirstlane(rowptr4[w * 4 + 1]);
    int b2 = __builtin_amdgcn_readfirstlane(rowptr4[w * 4 + 2]);
    int b3 = __builtin_amdgcn_readfirstlane(rowptr4[w * 4 + 3]);
    int b4 = __builtin_amdgcn_readfirstlane(rowptr4[w * 4 + 4]);  // sentinel-backed

    float s0 = 0.f, s1 = 0.f;
    float sn0[3], sn1[3];

    int e = b0;
    while (e + 8 <= b4) {
        int p[8];
        unsigned int u[8];
#pragma unroll
        for (int i = 0; i < 8; ++i) p[i] = csr[e + i];
#pragma unroll
        for (int i = 0; i < 8; ++i) u[i] = hbu[(size_t)p[i] * 64 + lane];
#pragma unroll
        for (int i = 0; i < 8; ++i) {
            int idx = e + i;
            if (idx == b1) { sn0[0] = s0; sn1[0] = s1; }
            if (idx == b2) { sn0[1] = s0; sn1[1] = s1; }
            if (idx == b3) { sn0[2] = s0; sn1[2] = s1; }
            s0 += bf2f(u[i] & 0xffffu);
            s1 += bf2f(u[i] >> 16);
        }
        e += 8;
    }
    {   // tail: 0..7 edges, uniform predication
        int rem = b4 - e;
        int p[7];
        unsigned int u[7];
#pragma unroll
        for (int i = 0; i < 7; ++i) if (i < rem) p[i] = csr[e + i];
#pragma unroll
        for (int i = 0; i < 7; ++i) if (i < rem) u[i] = hbu[(size_t)p[i] * 64 + lane];
#pragma unroll
        for (int i = 0; i < 7; ++i) {
            if (i < rem) {
                int idx = e + i;
                if (idx == b1) { sn0[0] = s0; sn1[0] = s1; }
                if (idx == b2) { sn0[1] = s0; sn1[1] = s1; }
                if (idx == b3) { sn0[2] = s0; sn1[2] = s1; }
                s0 += bf2f(u[i] & 0xffffu);
                s1 += bf2f(u[i] >> 16);
            }
        }
    }
    if (b1 == b4) { sn0[0] = s0; sn1[0] = s1; }
    if (b2 == b4) { sn0[1] = s0; sn1[1] = s1; }
    if (b3 == b4) { sn0[2] = s0; sn1[2] = s1; }

    size_t base = (size_t)w * 256 + lane;
    float a0, a1, p0 = 0.f, p1 = 0.f;
#pragma unroll
    for (int t = 0; t < 4; ++t) {
        float c0 = (t < 3) ? sn0[t] : s0;
        float c1 = (t < 3) ? sn1[t] : s1;
        a0 = c0 - p0; a1 = c1 - p1;
        p0 = c0; p1 = c1;
        Su[base + t * 64] = (unsigned int)f2bf(a0) | ((unsigned int)f2bf(a1) << 16);
    }
    if (lane == 0)
        cnt4[w] = make_float4((float)(b1 - b0), (float)(b2 - b1),
                              (float)(b3 - b2), (float)(b4 - b3));
}

// ---- agg_gru v6: LDS-both-operands + parity dbuf pipelining, BK=64 --------
// 64-node tile, 512 threads (8 waves).  LDS 64KB:
//   Sd:   [2][64 rows][64 sh]  @0      (16KB)   phase A activation slices
//   Wd:   [2][128 rows][64 sh] @16384  (32KB)   Wc / Wg slices
//   Xagg: [64][128 sh]         @49152  (16KB)   agg handoff
//   Hbt:  [64][128 sh]         @0      (16KB)   h tile (phase B, over Sd)
//   Outs: [64][128 f32]        @0      (32KB)   epilogue overlay
// Swizzle: 16B group g of row r stored at g^(r&7) (BK=64: g in 0..7;
// 128-sh rows: g in 0..15, XOR low 3 bits).  Reads use same XOR.
// Per step: issue next global loads -> ds_write current -> barrier ->
// MFMA from LDS.  One barrier/step; parity covers WAR (R13-verified).

__global__ __launch_bounds__(512, 4) void agg_gru(const unsigned short* __restrict__ S,
                                                  const unsigned short* __restrict__ Wc,
                                                  const unsigned short* __restrict__ Wg,
                                                  const unsigned short* __restrict__ hbf,
                                                  const float4* __restrict__ cnt4,
                                                  const float* __restrict__ eb,
                                                  const float4* __restrict__ bias4,
                                                  float* __restrict__ out, int M) {
    __shared__ __align__(16) unsigned char smem[65536];
    unsigned short* SdB = (unsigned short*)smem;            // + p*4096 shorts
    unsigned short* WdB = (unsigned short*)(smem + 16384);  // + p*8192 shorts
    unsigned short* Xag = (unsigned short*)(smem + 49152);
    unsigned short* Hbt = (unsigned short*)smem;            // phase B overlay
    float* OutsF = (float*)smem;                            // epilogue overlay

    const int tid = threadIdx.x;
    const int m0 = blockIdx.x * 64;
    const int lane = tid & 63, w = tid >> 6;
    const int lm = lane & 15, quad = lane >> 4;

    // staging geometry (64-short rows): thread covers row tid>>3, group tid&7
    const int sr = tid >> 3;          // 0..63
    const int g8 = tid & 7;           // group 0..7
    const int srow = (m0 + sr < M) ? (m0 + sr) : (M - 1);   // clamped S row

    // ---- phase A: 8 steps, BK=64, parity dbuf ----
    floatx4 accA[4];
#pragma unroll
    for (int a = 0; a < 4; ++a) accA[a] = (floatx4){0.f, 0.f, 0.f, 0.f};

    uint4 sv  = *(const uint4*)(S + (size_t)srow * 512 + g8 * 8);
    uint4 wv0 = *(const uint4*)(Wc + (size_t)sr * 512 + g8 * 8);
    uint4 wv1 = *(const uint4*)(Wc + (size_t)(64 + sr) * 512 + g8 * 8);

#pragma unroll 1
    for (int c = 0; c < 8; ++c) {
        uint4 sn, wn0, wn1;
        if (c < 7) {   // issue next-step loads EARLY
            sn  = *(const uint4*)(S + (size_t)srow * 512 + (c + 1) * 64 + g8 * 8);
            wn0 = *(const uint4*)(Wc + (size_t)sr * 512 + (c + 1) * 64 + g8 * 8);
            wn1 = *(const uint4*)(Wc + (size_t)(64 + sr) * 512 + (c + 1) * 64 + g8 * 8);
        }
        unsigned short* Sp = SdB + (c & 1) * 4096;
        unsigned short* Wp = WdB + (c & 1) * 8192;
        *(uint4*)&Sp[sr * 64 + ((g8 ^ (sr & 7)) << 3)] = sv;
        *(uint4*)&Wp[sr * 64 + ((g8 ^ (sr & 7)) << 3)] = wv0;
        *(uint4*)&Wp[(64 + sr) * 64 + ((g8 ^ (sr & 7)) << 3)] = wv1;
        __syncthreads();
#pragma unroll
        for (int ks = 0; ks < 2; ++ks) {
            int g = ks * 4 + quad;
            short8 bw = *(const short8*)&Wp[(w * 16 + lm) * 64 + ((g ^ (lm & 7)) << 3)];
#pragma unroll
            for (int mi = 0; mi < 4; ++mi) {
                short8 av = *(const short8*)&Sp[(mi * 16 + lm) * 64 + ((g ^ (lm & 7)) << 3)];
                accA[mi] = __builtin_amdgcn_mfma_f32_16x16x32_bf16(av, bw, accA[mi], 0, 0, 0);
            }
        }
        sv = sn; wv0 = wn0; wv1 = wn1;
        // no trailing barrier: parity dbuf (R13-verified WAR coverage)
    }

    // handoff: agg(+cnt.eb) -> Xagg (swizzled scalar writes; v5-verified)
    {
        int j = w * 16 + lm;
        float e0 = eb[j], e1 = eb[HID + j], e2 = eb[2 * HID + j], e3 = eb[3 * HID + j];
        int jg = j >> 3, jr = j & 7;
#pragma unroll
        for (int mi = 0; mi < 4; ++mi) {
#pragma unroll
            for (int r = 0; r < 4; ++r) {
                int nl = mi * 16 + quad * 4 + r;
                int gn = m0 + nl;
                if (gn >= M) gn = M - 1;
                float4 c4 = cnt4[gn];
                float v = accA[mi][r] + c4.x * e0 + c4.y * e1 + c4.z * e2 + c4.w * e3;
                Xag[nl * 128 + ((jg ^ (nl & 7)) << 3) + jr] = f2bf(v);
            }
        }
    }
    __syncthreads();  // phase A Sd/Wd reads done; Xagg visible; Sd free

    // ---- phase B: 16 slices (gc 0..3 x kc 0..3), parity dbuf on Wd ----
    // stage Hbt (h tile, 128-sh rows): thread covers rows tid>>4 & 32+(tid>>4)
    {
        int hr = tid >> 4, sg = tid & 15;
        int ga = (m0 + hr < M) ? (m0 + hr) : (M - 1);
        int gb = (m0 + 32 + hr < M) ? (m0 + 32 + hr) : (M - 1);
        uint4 va = *(const uint4*)(hbf + (size_t)ga * HID + sg * 8);
        uint4 vb = *(const uint4*)(hbf + (size_t)gb * HID + sg * 8);
        *(uint4*)&Hbt[hr * 128 + ((sg ^ (hr & 7)) << 3)] = va;
        *(uint4*)&Hbt[(32 + hr) * 128 + ((sg ^ ((32 + hr) & 7)) << 3)] = vb;
    }

    // Wg slice rows: thread covers slice rows sr2a=tid>>3 (0..63), 64+sr2a
    uint4 w0 = *(const uint4*)(Wg + (size_t)sr * 256 + g8 * 8);          // slice 0 = gc0,kc0
    uint4 w1 = *(const uint4*)(Wg + (size_t)(64 + sr) * 256 + g8 * 8);

    floatx4 accB[4];
    float fin[4][4];

#pragma unroll 1
    for (int s = 0; s < 16; ++s) {
        int gc = s >> 2, kc = s & 3;
        uint4 n0, n1;
        if (s < 15) {   // issue next-slice loads EARLY
            int s1i = s + 1;
            int gcn = s1i >> 2, kcn = s1i & 3;
            const unsigned short* base = Wg + (size_t)(gcn * 128) * 256 + kcn * 64;
            n0 = *(const uint4*)(base + (size_t)sr * 256 + g8 * 8);
            n1 = *(const uint4*)(base + (size_t)(64 + sr) * 256 + g8 * 8);
        }
        unsigned short* Wp = WdB + (s & 1) * 8192;
        *(uint4*)&Wp[sr * 64 + ((g8 ^ (sr & 7)) << 3)] = w0;
        *(uint4*)&Wp[(64 + sr) * 64 + ((g8 ^ (sr & 7)) << 3)] = w1;
        __syncthreads();

        if (kc == 0) {
#pragma unroll
            for (int a = 0; a < 4; ++a) accB[a] = (floatx4){0.f, 0.f, 0.f, 0.f};
        }
        const unsigned short* Bsrc = (kc < 2) ? Xag : Hbt;
        const int kb = (kc & 1) * 8;
#pragma unroll
        for (int ks = 0; ks < 2; ++ks) {
            int g = ks * 4 + quad;
            short8 af = *(const short8*)&Wp[(w * 16 + lm) * 64 + ((g ^ (lm & 7)) << 3)];
            int G = kb + g;
#pragma unroll
            for (int ni = 0; ni < 4; ++ni) {
                int nl = ni * 16 + lm;
                short8 bfr = *(const short8*)&Bsrc[nl * 128 + ((G ^ (nl & 7)) << 3)];
                accB[ni] = __builtin_amdgcn_mfma_f32_16x16x32_bf16(af, bfr, accB[ni], 0, 0, 0);
            }
        }
        if (kc == 3) {
            // GRU math: gate row = gc*128 + w*16 + quad*4 + g -> j = gc*32+w*4+quad
            int j = gc * 32 + w * 4 + quad;
            float4 bb = bias4[j];
            int jg = j >> 3, jr = j & 7;
#pragma unroll
            for (int ni = 0; ni < 4; ++ni) {
                int nl = ni * 16 + lm;
                float g0 = accB[ni][0], g1 = accB[ni][1];
                float g2 = accB[ni][2], g3 = accB[ni][3];
                float rr = frcp(1.f + __expf(-(g0 + bb.x)));
                float zz = frcp(1.f + __expf(-(g1 + bb.y)));
                float aa = g2 + bb.z + rr * (g3 + bb.w);
                float nn = 1.f - 2.f * frcp(1.f + __expf(2.f * aa));  // tanh
                float hv = bf2f((unsigned int)Hbt[nl * 128 + ((jg ^ (nl & 7)) << 3) + jr]);
                fin[gc][ni] = nn + zz * (hv - nn);
            }
        }
        w0 = n0; w1 = n1;
    }
    __syncthreads();  // all LDS reads done -> Outs overlay safe

    // write fin -> Outs (f32, swizzled: 4-float group gq at gq^(row&7))
#pragma unroll
    for (int gc = 0; gc < 4; ++gc) {
        int j = gc * 32 + w * 4 + quad;
        int gq = j >> 2, jr = j & 3;
#pragma unroll
        for (int ni = 0; ni < 4; ++ni) {
            int nl = ni * 16 + lm;
            OutsF[nl * 128 + ((gq ^ (nl & 7)) << 2) + jr] = fin[gc][ni];
        }
    }
    __syncthreads();

    // coalesced store: 64 nodes x 128 floats
    {
        int row = tid >> 3;              // 0..63
        int cb = (tid & 7) * 16;         // 0..112
        int node = m0 + row;
        if (node < M) {
            float* dstp = out + (size_t)node * HID + cb;
#pragma unroll
            for (int i = 0; i < 4; ++i) {
                int gq = (cb >> 2) + i;
                *(float4*)(dstp + i * 4) = *(const float4*)&OutsF[row * 128 + ((gq ^ (row & 7)) << 2)];
            }
        }
    }
}

// ---------------------------------------------------------------------------

extern "C" void kernel_launch(void* const* d_in, const int* in_sizes, int n_in,
                              void* d_out, int out_size, void* d_ws, size_t ws_size,
                              hipStream_t stream) {
    const float* node_states = (const float*)d_in[0];
    const int*   edge_index  = (const int*)d_in[1];
    const int*   edge_type   = (const int*)d_in[2];
    const float* edge_W      = (const float*)d_in[3];
    const float* edge_b      = (const float*)d_in[4];
    const float* w_ih        = (const float*)d_in[5];
    const float* w_hh        = (const float*)d_in[6];
    const float* b_ih        = (const float*)d_in[7];
    const float* b_hh        = (const float*)d_in[8];

    const int M = in_sizes[0] / HID;      // 50000 nodes
    const int E = in_sizes[1] / 2;        // 625000 edges
    const int N4 = M * 4;                 // 200000 (dst,type) segments
    const int* src = edge_index;
    const int* dst = edge_index + E;

    // workspace layout (~70 MB)
    char* ws = (char*)d_ws;
    size_t off = 0;
    unsigned short* hbf   = (unsigned short*)(ws + off); off += (size_t)M * HID * 2;    // 12.8MB
    float*          bias4 = (float*)(ws + off);          off += (size_t)128 * 4 * 4;    // 2KB
    unsigned short* S     = (unsigned short*)(ws + off); off += (size_t)M * 512 * 2;    // 51.2MB
    unsigned short* Wcat  = (unsigned short*)(ws + off); off += (size_t)128 * 512 * 2;  // 128KB
    unsigned short* Wgru  = (unsigned short*)(ws + off); off += (size_t)512 * 256 * 2;  // 256KB
    float*          cnt4  = (float*)(ws + off);          off += (size_t)M * 4 * 4;      // 800KB
    int* deg4     = (int*)(ws + off); off += (size_t)N4 * 4;
    int* rowptr4  = (int*)(ws + off); off += (size_t)(N4 + 1) * 4;
    int* cursor4  = (int*)(ws + off); off += (size_t)N4 * 4;
    int* blocksum = (int*)(ws + off); off += 256 * 4;
    int* blockoff = (int*)(ws + off); off += 256 * 4;
    int* csr      = (int*)(ws + off); off += (size_t)E * 4;

    const int total4 = M * HID / 4;
    const int nb_cvt = (total4 + 255) / 256;     // 6250

    prep_kernel<<<nb_cvt + 769, 256, 0, stream>>>(
        node_states, hbf, edge_W, Wcat, w_ih, w_hh, Wgru, bias4, b_ih, b_hh,
        total4, nb_cvt);

    CsrArgs ca;
    ca.src = src; ca.dst = dst; ca.ety = edge_type;
    ca.deg4 = deg4; ca.rowptr4 = rowptr4; ca.cursor4 = cursor4;
    ca.blocksum = blocksum; ca.blockoff = blockoff; ca.csr = csr;
    ca.E = E; ca.N4 = N4;
    void* params[] = {&ca};
    hipLaunchCooperativeKernel((void*)csr_build, dim3(1024), dim3(256),
                               params, 0, stream);

    gather_s_kernel<<<(M + 3) / 4, 256, 0, stream>>>(rowptr4, csr, (const unsigned int*)hbf,
                                                     (float4*)cnt4, (unsigned int*)S, M);

    agg_gru<<<(M + 63) / 64, 512, 0, stream>>>(S, Wcat, Wgru, hbf, (const float4*)cnt4,
                                               edge_b, (const float4*)bias4, (float*)d_out, M);
}

// Round 9
// 245.865 us; speedup vs baseline: 3.3345x; 3.3345x over previous
//
#include <hip/hip_runtime.h>

// ---------------------------------------------------------------------------
// GGNN message passing, MI355X/gfx950.  Round 18 = R16 + agg_gru v7 retile.
//   R17 post-mortem: cooperative grid.sync costs ~100+us EACH on MI355X
//   (csr_build 620us with 0.2% VALU, 1.5% HBM) -- coop kernels BANNED.
//   R14's 662us was the same overhead, not gather serialization.
//   agg_gru v6 (weight-stage pipelining) ~= v5: null, dropped.
//   R16 agg_gru occupancy 28.6% root cause: 391 blocks / 256 CUs = 1.53
//   blocks/CU -- the GRID, not LDS, caps occupancy.
//   v7: v5's exact verified index algebra retiled to 32-node/256-thread
//   blocks -> 1563 blocks, 48KB LDS (Sreg/Xagg overlay 8K + Hbt 8K +
//   Wreg 32K; Outs overlays Wreg) -> 3 blocks/CU, fully packed.
// Lessons: no gather-into-GEMM fusion (R6); no K-merging (R7); LDS-staged
// coalesced out stores (R5); (dst,type) CSR (R6/R9); watch WRITE_SIZE for
// spill (R12); weights must be LDS-staged (R16); NO cooperative kernels
// (R14/R17); wave-per-node gather (R15).
// ---------------------------------------------------------------------------

typedef __attribute__((ext_vector_type(8))) short short8;
typedef __attribute__((ext_vector_type(4))) float floatx4;

#define HID 128
#define NTY 4

__device__ __forceinline__ unsigned short f2bf(float f) {
    unsigned int u = __float_as_uint(f);
    unsigned int r = (u + 0x7fffu + ((u >> 16) & 1u)) >> 16;  // RNE
    return (unsigned short)r;
}
__device__ __forceinline__ float bf2f(unsigned int lo16) {
    return __uint_as_float(lo16 << 16);
}
__device__ __forceinline__ float frcp(float x) { return __builtin_amdgcn_rcpf(x); }

// ---- prep: cvt_h | pack_wcat | pack_wgru | bias4 | zero deg4 --------------

__global__ void prep_kernel(const float* __restrict__ h, unsigned short* __restrict__ hbf,
                            const float* __restrict__ W, unsigned short* __restrict__ Wc,
                            const float* __restrict__ w_ih, const float* __restrict__ w_hh,
                            unsigned short* __restrict__ Wg, float* __restrict__ bias4,
                            const float* __restrict__ b_ih, const float* __restrict__ b_hh,
                            int* __restrict__ deg4, int total4, int nb_cvt, int N4) {
    int b = blockIdx.x, tt = threadIdx.x;
    if (b < nb_cvt) {
        int i = b * 256 + tt;
        if (i < total4) {
            float4 v = ((const float4*)h)[i];
            uint2 o;
            o.x = (unsigned int)f2bf(v.x) | ((unsigned int)f2bf(v.y) << 16);
            o.y = (unsigned int)f2bf(v.z) | ((unsigned int)f2bf(v.w) << 16);
            ((uint2*)hbf)[i] = o;
        }
    } else if (b < nb_cvt + 256) {
        // Wcat[j][t*128+k] = edge_W[t][j][k]  (128 x 512)
        int idx = (b - nb_cvt) * 256 + tt;
        int j = idx >> 9, rem = idx & 511;
        int t = rem >> 7, k = rem & 127;
        Wc[idx] = f2bf(W[(t * HID + j) * HID + k]);
    } else if (b < nb_cvt + 768) {
        // Wg[512][256]: rows 4j+{0,1,2,3} = r|z|i_n|h_n; cols 0-127 agg, 128-255 h
        int idx = (b - nb_cvt - 256) * 256 + tt;
        int row = idx >> 8, k = idx & 255;
        int j = row >> 2, g = row & 3;
        float v = 0.0f;
        if (g == 0) v = (k < 128) ? w_ih[j * 128 + k]         : w_hh[j * 128 + (k - 128)];
        else if (g == 1) v = (k < 128) ? w_ih[(128 + j) * 128 + k] : w_hh[(128 + j) * 128 + (k - 128)];
        else if (g == 2) v = (k < 128) ? w_ih[(256 + j) * 128 + k] : 0.0f;
        else             v = (k < 128) ? 0.0f : w_hh[(256 + j) * 128 + (k - 128)];
        Wg[idx] = f2bf(v);
    } else if (b == nb_cvt + 768) {
        if (tt < 128) {
            float4 v;
            v.x = b_ih[tt] + b_hh[tt];
            v.y = b_ih[128 + tt] + b_hh[128 + tt];
            v.z = b_ih[256 + tt];
            v.w = b_hh[256 + tt];
            ((float4*)bias4)[tt] = v;
        }
    } else {
        int i = (b - nb_cvt - 769) * 256 + tt;
        if (i < N4) deg4[i] = 0;
    }
}

// ---- (dst,type)-segmented CSR construction (R6, verified) -----------------

__global__ void hist4_kernel(const int* __restrict__ dst, const int* __restrict__ ety,
                             int* __restrict__ deg4, int E) {
    int e = blockIdx.x * blockDim.x + threadIdx.x;
    if (e < E) atomicAdd(&deg4[dst[e] * 4 + ety[e]], 1);
}

__global__ void scan_blocks4_kernel(const int* __restrict__ deg, int* __restrict__ rowptr,
                                    int* __restrict__ blocksum, int N4) {
    __shared__ int s[256];
    int t = threadIdx.x;
    int base = blockIdx.x * 1024 + t * 4;
    int v0 = 0, v1 = 0, v2 = 0, v3 = 0;
    if (base + 3 < N4) {
        v0 = deg[base]; v1 = deg[base + 1]; v2 = deg[base + 2]; v3 = deg[base + 3];
    } else {
        if (base < N4) v0 = deg[base];
        if (base + 1 < N4) v1 = deg[base + 1];
        if (base + 2 < N4) v2 = deg[base + 2];
    }
    int sum = v0 + v1 + v2 + v3;
    s[t] = sum;
    __syncthreads();
#pragma unroll
    for (int off = 1; off < 256; off <<= 1) {
        int x = (t >= off) ? s[t - off] : 0;
        __syncthreads();
        s[t] += x;
        __syncthreads();
    }
    int ex = s[t] - sum;
    if (base < N4) rowptr[base] = ex;
    if (base + 1 < N4) rowptr[base + 1] = ex + v0;
    if (base + 2 < N4) rowptr[base + 2] = ex + v0 + v1;
    if (base + 3 < N4) rowptr[base + 3] = ex + v0 + v1 + v2;
    if (t == 255) blocksum[blockIdx.x] = s[255];
}

__global__ void scan_top_kernel(const int* __restrict__ blocksum, int* __restrict__ blockoff, int nb) {
    __shared__ int s[256];
    int t = threadIdx.x;
    int v = (t < nb) ? blocksum[t] : 0;
    s[t] = v;
    __syncthreads();
#pragma unroll
    for (int off = 1; off < 256; off <<= 1) {
        int x = (t >= off) ? s[t - off] : 0;
        __syncthreads();
        s[t] += x;
        __syncthreads();
    }
    if (t < nb) blockoff[t] = s[t] - v;
}

__global__ void finalize4_kernel(int* __restrict__ rowptr, const int* __restrict__ blockoff,
                                 int* __restrict__ cursor, int N4, int E) {
    int i = blockIdx.x * blockDim.x + threadIdx.x;
    if (i >= N4) return;
    int r = rowptr[i] + blockoff[i >> 10];
    rowptr[i] = r;
    cursor[i] = r;
    if (i == 0) rowptr[N4] = E;  // sentinel
}

__global__ void fill4_kernel(const int* __restrict__ src, const int* __restrict__ dst,
                             const int* __restrict__ ety, int* __restrict__ cursor,
                             int* __restrict__ csr, int E) {
    int e = blockIdx.x * blockDim.x + threadIdx.x;
    if (e >= E) return;
    int pos = atomicAdd(&cursor[dst[e] * 4 + ety[e]], 1);
    csr[pos] = src[e];
}

// ---- gather_s v4 (R13/R16, measured-best): flat MLP-8 + snapshots ---------

__global__ void gather_s_kernel(const int* __restrict__ rowptr4, const int* __restrict__ csr,
                                const unsigned int* __restrict__ hbu,
                                float4* __restrict__ cnt4, unsigned int* __restrict__ Su, int N) {
    int w = blockIdx.x * (blockDim.x >> 6) + (threadIdx.x >> 6);
    if (w >= N) return;
    int lane = threadIdx.x & 63;
    int b0 = __builtin_amdgcn_readfirstlane(rowptr4[w * 4]);
    int b1 = __builtin_amdgcn_readfirstlane(rowptr4[w * 4 + 1]);
    int b2 = __builtin_amdgcn_readfirstlane(rowptr4[w * 4 + 2]);
    int b3 = __builtin_amdgcn_readfirstlane(rowptr4[w * 4 + 3]);
    int b4 = __builtin_amdgcn_readfirstlane(rowptr4[w * 4 + 4]);  // sentinel-backed

    float s0 = 0.f, s1 = 0.f;
    float sn0[3], sn1[3];

    int e = b0;
    while (e + 8 <= b4) {
        int p[8];
        unsigned int u[8];
#pragma unroll
        for (int i = 0; i < 8; ++i) p[i] = csr[e + i];
#pragma unroll
        for (int i = 0; i < 8; ++i) u[i] = hbu[(size_t)p[i] * 64 + lane];
#pragma unroll
        for (int i = 0; i < 8; ++i) {
            int idx = e + i;
            if (idx == b1) { sn0[0] = s0; sn1[0] = s1; }
            if (idx == b2) { sn0[1] = s0; sn1[1] = s1; }
            if (idx == b3) { sn0[2] = s0; sn1[2] = s1; }
            s0 += bf2f(u[i] & 0xffffu);
            s1 += bf2f(u[i] >> 16);
        }
        e += 8;
    }
    {   // tail: 0..7 edges, uniform predication
        int rem = b4 - e;
        int p[7];
        unsigned int u[7];
#pragma unroll
        for (int i = 0; i < 7; ++i) if (i < rem) p[i] = csr[e + i];
#pragma unroll
        for (int i = 0; i < 7; ++i) if (i < rem) u[i] = hbu[(size_t)p[i] * 64 + lane];
#pragma unroll
        for (int i = 0; i < 7; ++i) {
            if (i < rem) {
                int idx = e + i;
                if (idx == b1) { sn0[0] = s0; sn1[0] = s1; }
                if (idx == b2) { sn0[1] = s0; sn1[1] = s1; }
                if (idx == b3) { sn0[2] = s0; sn1[2] = s1; }
                s0 += bf2f(u[i] & 0xffffu);
                s1 += bf2f(u[i] >> 16);
            }
        }
    }
    if (b1 == b4) { sn0[0] = s0; sn1[0] = s1; }
    if (b2 == b4) { sn0[1] = s0; sn1[1] = s1; }
    if (b3 == b4) { sn0[2] = s0; sn1[2] = s1; }

    size_t base = (size_t)w * 256 + lane;
    float a0, a1, p0 = 0.f, p1 = 0.f;
#pragma unroll
    for (int t = 0; t < 4; ++t) {
        float c0 = (t < 3) ? sn0[t] : s0;
        float c1 = (t < 3) ? sn1[t] : s1;
        a0 = c0 - p0; a1 = c1 - p1;
        p0 = c0; p1 = c1;
        Su[base + t * 64] = (unsigned int)f2bf(a0) | ((unsigned int)f2bf(a1) << 16);
    }
    if (lane == 0)
        cnt4[w] = make_float4((float)(b1 - b0), (float)(b2 - b1),
                              (float)(b3 - b2), (float)(b4 - b3));
}

// ---- agg_gru v7: v5's verified math, 32-node tile, 256 threads, 48KB ------
// LDS: Sreg/Xagg overlay @0 (8KB) | Hbt @8192 (8KB) | Wreg @16384 (32KB);
// Outs f32 (16KB) overlays Wreg in the epilogue.
// Swizzle (v5-verified): 8-short group g of row r stored at g^(r&7).
// Phase A (c=0..3): stage Sreg[32][128] + Wreg[128][128] -> bar -> wave w
//   computes accA[mi][ni] for cols j=w*32+ni*16+lm (16 MFMA) -> bar.
// Handoff: agg(+cnt.eb) -> Xagg (Sreg region, dead after last barrier).
// Phase B (gc=0..3): per kc=0,1 stage Wreg=Wg[gc-chunk][kc-half] -> bar ->
//   8 MFMA (B = Xagg | Hbt) -> bar.  Wave owns chunk rows w*32+mi2*16+lm.
//   GRU math at kc=1 end: j = gc*32 + w*8 + mi2*4 + quad, gate = reg.
// Epilogue: fin[4][2][2] -> swizzled f32 Outs (over Wreg) -> float4 stores.

__global__ __launch_bounds__(256, 3) void agg_gru(const unsigned short* __restrict__ S,
                                                  const unsigned short* __restrict__ Wc,
                                                  const unsigned short* __restrict__ Wg,
                                                  const unsigned short* __restrict__ hbf,
                                                  const float4* __restrict__ cnt4,
                                                  const float* __restrict__ eb,
                                                  const float4* __restrict__ bias4,
                                                  float* __restrict__ out, int M) {
    __shared__ __align__(16) unsigned char smem[49152];
    unsigned short* Sreg = (unsigned short*)smem;            // 8KB; Xagg overlay
    unsigned short* Hbt  = (unsigned short*)(smem + 8192);   // 8KB
    unsigned short* Wreg = (unsigned short*)(smem + 16384);  // 32KB
    unsigned short* Xag  = Sreg;                             // overlay after phase A
    float* OutsF = (float*)(smem + 16384);                   // epilogue overlay

    const int tid = threadIdx.x;
    const int m0 = blockIdx.x * 32;
    const int lane = tid & 63, w = tid >> 6;   // w in 0..3
    const int lm = lane & 15, quad = lane >> 4;

    // staging geometry: 16 threads/row, 8-short group sg = tid&15
    const int hr = tid >> 4;          // 0..15
    const int sg = tid & 15;
    const int gA = (m0 + hr < M) ? (m0 + hr) : (M - 1);
    const int gB = (m0 + 16 + hr < M) ? (m0 + 16 + hr) : (M - 1);

    // ---- phase A: agg = S @ Wc^T, K=512, BK=128 ----
    floatx4 accA[2][2];
#pragma unroll
    for (int x = 0; x < 2; ++x)
#pragma unroll
        for (int y = 0; y < 2; ++y) accA[x][y] = (floatx4){0.f, 0.f, 0.f, 0.f};

#pragma unroll 1
    for (int c = 0; c < 4; ++c) {
        // stage S c-slice -> Sreg[32][128] (swizzled)
        {
            uint4 vA = *(const uint4*)(S + (size_t)gA * 512 + c * 128 + sg * 8);
            uint4 vB = *(const uint4*)(S + (size_t)gB * 512 + c * 128 + sg * 8);
            *(uint4*)&Sreg[hr * 128 + ((sg ^ (hr & 7)) << 3)] = vA;
            *(uint4*)&Sreg[(16 + hr) * 128 + ((sg ^ (hr & 7)) << 3)] = vB;
        }
        // stage Wc c-slice -> Wreg[128][128] (swizzled)
#pragma unroll
        for (int p = 0; p < 8; ++p) {
            int j = p * 16 + hr;
            uint4 v = *(const uint4*)(Wc + (size_t)j * 512 + c * 128 + sg * 8);
            *(uint4*)&Wreg[j * 128 + ((sg ^ (j & 7)) << 3)] = v;
        }
        __syncthreads();
#pragma unroll
        for (int ss = 0; ss < 4; ++ss) {
            int g = ss * 4 + quad;
            short8 av[2], bw[2];
#pragma unroll
            for (int mi = 0; mi < 2; ++mi)
                av[mi] = *(const short8*)&Sreg[(mi * 16 + lm) * 128 + ((g ^ (lm & 7)) << 3)];
#pragma unroll
            for (int ni = 0; ni < 2; ++ni)
                bw[ni] = *(const short8*)&Wreg[(w * 32 + ni * 16 + lm) * 128 + ((g ^ (lm & 7)) << 3)];
#pragma unroll
            for (int mi = 0; mi < 2; ++mi)
#pragma unroll
                for (int ni = 0; ni < 2; ++ni)
                    accA[mi][ni] = __builtin_amdgcn_mfma_f32_16x16x32_bf16(av[mi], bw[ni], accA[mi][ni], 0, 0, 0);
        }
        __syncthreads();   // WAR: next c overwrites Sreg/Wreg; last iter frees Sreg
    }

    // stage Hbt (h tile, 32 rows x 128, swizzled) -- independent region
    {
        uint4 vA = *(const uint4*)(hbf + (size_t)gA * HID + sg * 8);
        uint4 vB = *(const uint4*)(hbf + (size_t)gB * HID + sg * 8);
        *(uint4*)&Hbt[hr * 128 + ((sg ^ (hr & 7)) << 3)] = vA;
        *(uint4*)&Hbt[(16 + hr) * 128 + ((sg ^ (hr & 7)) << 3)] = vB;
    }

    // handoff: agg(+cnt.eb) -> Xagg (Sreg region; all phase-A reads fenced)
    {
#pragma unroll
        for (int ni = 0; ni < 2; ++ni) {
            int j = w * 32 + ni * 16 + lm;
            float e0 = eb[j], e1 = eb[HID + j], e2 = eb[2 * HID + j], e3 = eb[3 * HID + j];
            int jg = j >> 3, jr = j & 7;
#pragma unroll
            for (int mi = 0; mi < 2; ++mi) {
#pragma unroll
                for (int r = 0; r < 4; ++r) {
                    int nl = mi * 16 + quad * 4 + r;          // 0..31
                    int gn = m0 + nl;
                    if (gn >= M) gn = M - 1;
                    float4 c4 = cnt4[gn];
                    float v = accA[mi][ni][r] + c4.x * e0 + c4.y * e1 + c4.z * e2 + c4.w * e3;
                    Xag[nl * 128 + ((jg ^ (nl & 7)) << 3) + jr] = f2bf(v);
                }
            }
        }
    }
    __syncthreads();  // Xagg + Hbt visible to all waves

    // ---- phase B: 4 gate chunks x 2 kc halves ----
    float fin[4][2][2];

#pragma unroll 1
    for (int gc = 0; gc < 4; ++gc) {
        floatx4 acc2[2][2];
#pragma unroll
        for (int x = 0; x < 2; ++x)
#pragma unroll
            for (int y = 0; y < 2; ++y) acc2[x][y] = (floatx4){0.f, 0.f, 0.f, 0.f};

#pragma unroll 1
        for (int kc = 0; kc < 2; ++kc) {
            // stage Wg chunk slice (128 rows x 128 cols) -> Wreg (swizzled)
#pragma unroll
            for (int p = 0; p < 8; ++p) {
                int rr = p * 16 + hr;                      // 0..127 in chunk
                uint4 v = *(const uint4*)(Wg + (size_t)(gc * 128 + rr) * 256 + kc * 128 + sg * 8);
                *(uint4*)&Wreg[rr * 128 + ((sg ^ (rr & 7)) << 3)] = v;
            }
            __syncthreads();
            const unsigned short* Bsrc = kc ? Hbt : Xag;
#pragma unroll
            for (int ss = 0; ss < 4; ++ss) {
                int g = ss * 4 + quad;
                short8 af[2], bfr[2];
#pragma unroll
                for (int mi2 = 0; mi2 < 2; ++mi2)
                    af[mi2] = *(const short8*)&Wreg[(w * 32 + mi2 * 16 + lm) * 128 + ((g ^ (lm & 7)) << 3)];
#pragma unroll
                for (int ni = 0; ni < 2; ++ni)
                    bfr[ni] = *(const short8*)&Bsrc[(ni * 16 + lm) * 128 + ((g ^ (lm & 7)) << 3)];
#pragma unroll
                for (int mi2 = 0; mi2 < 2; ++mi2)
#pragma unroll
                    for (int ni = 0; ni < 2; ++ni)
                        acc2[mi2][ni] = __builtin_amdgcn_mfma_f32_16x16x32_bf16(af[mi2], bfr[ni], acc2[mi2][ni], 0, 0, 0);
            }
            __syncthreads();  // WAR before next Wg stage
        }

        // GRU math: gate row = gc*128 + w*32 + mi2*16 + quad*4 + g
        //   -> j = gc*32 + w*8 + mi2*4 + quad, gate g = reg index
#pragma unroll
        for (int mi2 = 0; mi2 < 2; ++mi2) {
            int j = gc * 32 + w * 8 + mi2 * 4 + quad;   // 0..127
            float4 bb = bias4[j];                       // {b_r,b_z,b_in,b_hn}
            int jg = j >> 3, jr = j & 7;
#pragma unroll
            for (int ni = 0; ni < 2; ++ni) {
                int nl = ni * 16 + lm;
                float g0 = acc2[mi2][ni][0], g1 = acc2[mi2][ni][1];
                float g2 = acc2[mi2][ni][2], g3 = acc2[mi2][ni][3];
                float rr = frcp(1.f + __expf(-(g0 + bb.x)));
                float zz = frcp(1.f + __expf(-(g1 + bb.y)));
                float aa = g2 + bb.z + rr * (g3 + bb.w);
                float nn = 1.f - 2.f * frcp(1.f + __expf(2.f * aa));  // tanh
                float hv = bf2f((unsigned int)Hbt[nl * 128 + ((jg ^ (nl & 7)) << 3) + jr]);
                fin[gc][mi2][ni] = nn + zz * (hv - nn);
            }
        }
    }
    __syncthreads();  // all Wreg/Hbt/Xag reads done -> Outs overlay safe

    // fin -> Outs (f32, swizzled: 4-float group gq at gq^(row&7))
#pragma unroll
    for (int gc = 0; gc < 4; ++gc) {
#pragma unroll
        for (int mi2 = 0; mi2 < 2; ++mi2) {
            int j = gc * 32 + w * 8 + mi2 * 4 + quad;
            int gq = j >> 2, jr = j & 3;
#pragma unroll
            for (int ni = 0; ni < 2; ++ni) {
                int nl = ni * 16 + lm;
                OutsF[nl * 128 + ((gq ^ (nl & 7)) << 2) + jr] = fin[gc][mi2][ni];
            }
        }
    }
    __syncthreads();

    // coalesced store: 32 nodes x 128 floats
    {
        int row = tid >> 3;              // 0..31
        int cb = (tid & 7) * 16;         // 0..112
        int node = m0 + row;
        if (node < M) {
            float* dstp = out + (size_t)node * HID + cb;
#pragma unroll
            for (int i = 0; i < 4; ++i) {
                int gq = (cb >> 2) + i;
                *(float4*)(dstp + i * 4) = *(const float4*)&OutsF[row * 128 + ((gq ^ (row & 7)) << 2)];
            }
        }
    }
}

// ---------------------------------------------------------------------------

extern "C" void kernel_launch(void* const* d_in, const int* in_sizes, int n_in,
                              void* d_out, int out_size, void* d_ws, size_t ws_size,
                              hipStream_t stream) {
    const float* node_states = (const float*)d_in[0];
    const int*   edge_index  = (const int*)d_in[1];
    const int*   edge_type   = (const int*)d_in[2];
    const float* edge_W      = (const float*)d_in[3];
    const float* edge_b      = (const float*)d_in[4];
    const float* w_ih        = (const float*)d_in[5];
    const float* w_hh        = (const float*)d_in[6];
    const float* b_ih        = (const float*)d_in[7];
    const float* b_hh        = (const float*)d_in[8];

    const int M = in_sizes[0] / HID;      // 50000 nodes
    const int E = in_sizes[1] / 2;        // 625000 edges
    const int N4 = M * 4;                 // 200000 (dst,type) segments
    const int* src = edge_index;
    const int* dst = edge_index + E;

    // workspace layout (~70 MB)
    char* ws = (char*)d_ws;
    size_t off = 0;
    unsigned short* hbf   = (unsigned short*)(ws + off); off += (size_t)M * HID * 2;    // 12.8MB
    float*          bias4 = (float*)(ws + off);          off += (size_t)128 * 4 * 4;    // 2KB
    unsigned short* S     = (unsigned short*)(ws + off); off += (size_t)M * 512 * 2;    // 51.2MB
    unsigned short* Wcat  = (unsigned short*)(ws + off); off += (size_t)128 * 512 * 2;  // 128KB
    unsigned short* Wgru  = (unsigned short*)(ws + off); off += (size_t)512 * 256 * 2;  // 256KB
    float*          cnt4  = (float*)(ws + off);          off += (size_t)M * 4 * 4;      // 800KB
    int* deg4     = (int*)(ws + off); off += (size_t)N4 * 4;
    int* rowptr4  = (int*)(ws + off); off += (size_t)(N4 + 1) * 4;
    int* cursor4  = (int*)(ws + off); off += (size_t)N4 * 4;
    int* blocksum = (int*)(ws + off); off += 256 * 4;
    int* blockoff = (int*)(ws + off); off += 256 * 4;
    int* csr      = (int*)(ws + off); off += (size_t)E * 4;

    const int total4 = M * HID / 4;
    const int nb_cvt = (total4 + 255) / 256;     // 6250
    const int nb_zero = (N4 + 255) / 256;        // 782
    const int nb_scan = (N4 + 1023) / 1024;      // 196 <= 256

    prep_kernel<<<nb_cvt + 769 + nb_zero, 256, 0, stream>>>(
        node_states, hbf, edge_W, Wcat, w_ih, w_hh, Wgru, bias4, b_ih, b_hh,
        deg4, total4, nb_cvt, N4);

    hist4_kernel<<<(E + 255) / 256, 256, 0, stream>>>(dst, edge_type, deg4, E);
    scan_blocks4_kernel<<<nb_scan, 256, 0, stream>>>(deg4, rowptr4, blocksum, N4);
    scan_top_kernel<<<1, 256, 0, stream>>>(blocksum, blockoff, nb_scan);
    finalize4_kernel<<<(N4 + 255) / 256, 256, 0, stream>>>(rowptr4, blockoff, cursor4, N4, E);
    fill4_kernel<<<(E + 255) / 256, 256, 0, stream>>>(src, dst, edge_type, cursor4, csr, E);

    gather_s_kernel<<<(M + 3) / 4, 256, 0, stream>>>(rowptr4, csr, (const unsigned int*)hbf,
                                                     (float4*)cnt4, (unsigned int*)S, M);

    agg_gru<<<(M + 31) / 32, 256, 0, stream>>>(S, Wcat, Wgru, hbf, (const float4*)cnt4,
                                               edge_b, (const float4*)bias4, (float*)d_out, M);
}

// Round 10
// 243.789 us; speedup vs baseline: 3.3629x; 1.0085x over previous
//
#include <hip/hip_runtime.h>

// ---------------------------------------------------------------------------
// GGNN message passing, MI355X/gfx950.  Round 19 = R18 + agg_gru v8:
//   staging via __builtin_amdgcn_global_load_lds (width=16 DMA).
//   R18 post-mortem: retile null (67us invariant across 512t/64KB and
//   256t/48KB; occupancy FELL to 24%) -- grid/LDS/block size not binding.
//   Residual: reg-staged global->VGPR->ds_write round-trip (VALU 19%) +
//   staging ds_write bank conflicts (5.2M).  v8 deletes both: linear LDS
//   dest + INVERSE-swizzled per-lane global source + XOR on read
//   (both-sides-or-neither, m173/m201) -> LDS contents byte-identical to
//   v7; all MFMA/handoff/epilogue indexing verbatim from passing R18.
// Lessons: no gather-into-GEMM fusion (R6); no K-merging (R7); LDS-staged
// coalesced out stores (R5); (dst,type) CSR (R6/R9); watch WRITE_SIZE for
// spill (R12); weights must be LDS-staged (R16); NO cooperative kernels
// (R14/R17); wave-per-node gather (R15); tile/grid retunes null (R18).
// ---------------------------------------------------------------------------

typedef __attribute__((ext_vector_type(8))) short short8;
typedef __attribute__((ext_vector_type(4))) float floatx4;

#define HID 128
#define NTY 4

__device__ __forceinline__ unsigned short f2bf(float f) {
    unsigned int u = __float_as_uint(f);
    unsigned int r = (u + 0x7fffu + ((u >> 16) & 1u)) >> 16;  // RNE
    return (unsigned short)r;
}
__device__ __forceinline__ float bf2f(unsigned int lo16) {
    return __uint_as_float(lo16 << 16);
}
__device__ __forceinline__ float frcp(float x) { return __builtin_amdgcn_rcpf(x); }

// 16B global->LDS DMA: per-lane global src, wave-uniform LDS base + lane*16.
__device__ __forceinline__ void gload16(const unsigned short* g, unsigned short* l) {
    __builtin_amdgcn_global_load_lds(
        (const __attribute__((address_space(1))) unsigned int*)g,
        (__attribute__((address_space(3))) unsigned int*)l,
        16, 0, 0);
}

// ---- prep: cvt_h | pack_wcat | pack_wgru | bias4 | zero deg4 --------------

__global__ void prep_kernel(const float* __restrict__ h, unsigned short* __restrict__ hbf,
                            const float* __restrict__ W, unsigned short* __restrict__ Wc,
                            const float* __restrict__ w_ih, const float* __restrict__ w_hh,
                            unsigned short* __restrict__ Wg, float* __restrict__ bias4,
                            const float* __restrict__ b_ih, const float* __restrict__ b_hh,
                            int* __restrict__ deg4, int total4, int nb_cvt, int N4) {
    int b = blockIdx.x, tt = threadIdx.x;
    if (b < nb_cvt) {
        int i = b * 256 + tt;
        if (i < total4) {
            float4 v = ((const float4*)h)[i];
            uint2 o;
            o.x = (unsigned int)f2bf(v.x) | ((unsigned int)f2bf(v.y) << 16);
            o.y = (unsigned int)f2bf(v.z) | ((unsigned int)f2bf(v.w) << 16);
            ((uint2*)hbf)[i] = o;
        }
    } else if (b < nb_cvt + 256) {
        // Wcat[j][t*128+k] = edge_W[t][j][k]  (128 x 512)
        int idx = (b - nb_cvt) * 256 + tt;
        int j = idx >> 9, rem = idx & 511;
        int t = rem >> 7, k = rem & 127;
        Wc[idx] = f2bf(W[(t * HID + j) * HID + k]);
    } else if (b < nb_cvt + 768) {
        // Wg[512][256]: rows 4j+{0,1,2,3} = r|z|i_n|h_n; cols 0-127 agg, 128-255 h
        int idx = (b - nb_cvt - 256) * 256 + tt;
        int row = idx >> 8, k = idx & 255;
        int j = row >> 2, g = row & 3;
        float v = 0.0f;
        if (g == 0) v = (k < 128) ? w_ih[j * 128 + k]         : w_hh[j * 128 + (k - 128)];
        else if (g == 1) v = (k < 128) ? w_ih[(128 + j) * 128 + k] : w_hh[(128 + j) * 128 + (k - 128)];
        else if (g == 2) v = (k < 128) ? w_ih[(256 + j) * 128 + k] : 0.0f;
        else             v = (k < 128) ? 0.0f : w_hh[(256 + j) * 128 + (k - 128)];
        Wg[idx] = f2bf(v);
    } else if (b == nb_cvt + 768) {
        if (tt < 128) {
            float4 v;
            v.x = b_ih[tt] + b_hh[tt];
            v.y = b_ih[128 + tt] + b_hh[128 + tt];
            v.z = b_ih[256 + tt];
            v.w = b_hh[256 + tt];
            ((float4*)bias4)[tt] = v;
        }
    } else {
        int i = (b - nb_cvt - 769) * 256 + tt;
        if (i < N4) deg4[i] = 0;
    }
}

// ---- (dst,type)-segmented CSR construction (R6, verified) -----------------

__global__ void hist4_kernel(const int* __restrict__ dst, const int* __restrict__ ety,
                             int* __restrict__ deg4, int E) {
    int e = blockIdx.x * blockDim.x + threadIdx.x;
    if (e < E) atomicAdd(&deg4[dst[e] * 4 + ety[e]], 1);
}

__global__ void scan_blocks4_kernel(const int* __restrict__ deg, int* __restrict__ rowptr,
                                    int* __restrict__ blocksum, int N4) {
    __shared__ int s[256];
    int t = threadIdx.x;
    int base = blockIdx.x * 1024 + t * 4;
    int v0 = 0, v1 = 0, v2 = 0, v3 = 0;
    if (base + 3 < N4) {
        v0 = deg[base]; v1 = deg[base + 1]; v2 = deg[base + 2]; v3 = deg[base + 3];
    } else {
        if (base < N4) v0 = deg[base];
        if (base + 1 < N4) v1 = deg[base + 1];
        if (base + 2 < N4) v2 = deg[base + 2];
    }
    int sum = v0 + v1 + v2 + v3;
    s[t] = sum;
    __syncthreads();
#pragma unroll
    for (int off = 1; off < 256; off <<= 1) {
        int x = (t >= off) ? s[t - off] : 0;
        __syncthreads();
        s[t] += x;
        __syncthreads();
    }
    int ex = s[t] - sum;
    if (base < N4) rowptr[base] = ex;
    if (base + 1 < N4) rowptr[base + 1] = ex + v0;
    if (base + 2 < N4) rowptr[base + 2] = ex + v0 + v1;
    if (base + 3 < N4) rowptr[base + 3] = ex + v0 + v1 + v2;
    if (t == 255) blocksum[blockIdx.x] = s[255];
}

__global__ void scan_top_kernel(const int* __restrict__ blocksum, int* __restrict__ blockoff, int nb) {
    __shared__ int s[256];
    int t = threadIdx.x;
    int v = (t < nb) ? blocksum[t] : 0;
    s[t] = v;
    __syncthreads();
#pragma unroll
    for (int off = 1; off < 256; off <<= 1) {
        int x = (t >= off) ? s[t - off] : 0;
        __syncthreads();
        s[t] += x;
        __syncthreads();
    }
    if (t < nb) blockoff[t] = s[t] - v;
}

__global__ void finalize4_kernel(int* __restrict__ rowptr, const int* __restrict__ blockoff,
                                 int* __restrict__ cursor, int N4, int E) {
    int i = blockIdx.x * blockDim.x + threadIdx.x;
    if (i >= N4) return;
    int r = rowptr[i] + blockoff[i >> 10];
    rowptr[i] = r;
    cursor[i] = r;
    if (i == 0) rowptr[N4] = E;  // sentinel
}

__global__ void fill4_kernel(const int* __restrict__ src, const int* __restrict__ dst,
                             const int* __restrict__ ety, int* __restrict__ cursor,
                             int* __restrict__ csr, int E) {
    int e = blockIdx.x * blockDim.x + threadIdx.x;
    if (e >= E) return;
    int pos = atomicAdd(&cursor[dst[e] * 4 + ety[e]], 1);
    csr[pos] = src[e];
}

// ---- gather_s v4 (R13/R16, measured-best): flat MLP-8 + snapshots ---------

__global__ void gather_s_kernel(const int* __restrict__ rowptr4, const int* __restrict__ csr,
                                const unsigned int* __restrict__ hbu,
                                float4* __restrict__ cnt4, unsigned int* __restrict__ Su, int N) {
    int w = blockIdx.x * (blockDim.x >> 6) + (threadIdx.x >> 6);
    if (w >= N) return;
    int lane = threadIdx.x & 63;
    int b0 = __builtin_amdgcn_readfirstlane(rowptr4[w * 4]);
    int b1 = __builtin_amdgcn_readfirstlane(rowptr4[w * 4 + 1]);
    int b2 = __builtin_amdgcn_readfirstlane(rowptr4[w * 4 + 2]);
    int b3 = __builtin_amdgcn_readfirstlane(rowptr4[w * 4 + 3]);
    int b4 = __builtin_amdgcn_readfirstlane(rowptr4[w * 4 + 4]);  // sentinel-backed

    float s0 = 0.f, s1 = 0.f;
    float sn0[3], sn1[3];

    int e = b0;
    while (e + 8 <= b4) {
        int p[8];
        unsigned int u[8];
#pragma unroll
        for (int i = 0; i < 8; ++i) p[i] = csr[e + i];
#pragma unroll
        for (int i = 0; i < 8; ++i) u[i] = hbu[(size_t)p[i] * 64 + lane];
#pragma unroll
        for (int i = 0; i < 8; ++i) {
            int idx = e + i;
            if (idx == b1) { sn0[0] = s0; sn1[0] = s1; }
            if (idx == b2) { sn0[1] = s0; sn1[1] = s1; }
            if (idx == b3) { sn0[2] = s0; sn1[2] = s1; }
            s0 += bf2f(u[i] & 0xffffu);
            s1 += bf2f(u[i] >> 16);
        }
        e += 8;
    }
    {   // tail: 0..7 edges, uniform predication
        int rem = b4 - e;
        int p[7];
        unsigned int u[7];
#pragma unroll
        for (int i = 0; i < 7; ++i) if (i < rem) p[i] = csr[e + i];
#pragma unroll
        for (int i = 0; i < 7; ++i) if (i < rem) u[i] = hbu[(size_t)p[i] * 64 + lane];
#pragma unroll
        for (int i = 0; i < 7; ++i) {
            if (i < rem) {
                int idx = e + i;
                if (idx == b1) { sn0[0] = s0; sn1[0] = s1; }
                if (idx == b2) { sn0[1] = s0; sn1[1] = s1; }
                if (idx == b3) { sn0[2] = s0; sn1[2] = s1; }
                s0 += bf2f(u[i] & 0xffffu);
                s1 += bf2f(u[i] >> 16);
            }
        }
    }
    if (b1 == b4) { sn0[0] = s0; sn1[0] = s1; }
    if (b2 == b4) { sn0[1] = s0; sn1[1] = s1; }
    if (b3 == b4) { sn0[2] = s0; sn1[2] = s1; }

    size_t base = (size_t)w * 256 + lane;
    float a0, a1, p0 = 0.f, p1 = 0.f;
#pragma unroll
    for (int t = 0; t < 4; ++t) {
        float c0 = (t < 3) ? sn0[t] : s0;
        float c1 = (t < 3) ? sn1[t] : s1;
        a0 = c0 - p0; a1 = c1 - p1;
        p0 = c0; p1 = c1;
        Su[base + t * 64] = (unsigned int)f2bf(a0) | ((unsigned int)f2bf(a1) << 16);
    }
    if (lane == 0)
        cnt4[w] = make_float4((float)(b1 - b0), (float)(b2 - b1),
                              (float)(b3 - b2), (float)(b4 - b3));
}

// ---- agg_gru v8: v7 + global_load_lds staging -----------------------------
// 32-node tile, 256 threads (4 waves), 48KB LDS:
//   Sreg/Xagg overlay @0 (8KB) | Hbt @8192 (8KB) | Wreg @16384 (32KB);
//   OutsF (16KB) overlays Wreg in the epilogue.
// Staging = gload16 DMA: LDS linear, global source INVERSE-swizzled so LDS
// content is byte-identical to v7 (LDS[row][x] = global[row][x^(row&7)]).
// Reads (XOR), handoff, GRU, epilogue: verbatim R18 v7 (passed, 67us).

__global__ __launch_bounds__(256, 3) void agg_gru(const unsigned short* __restrict__ S,
                                                  const unsigned short* __restrict__ Wc,
                                                  const unsigned short* __restrict__ Wg,
                                                  const unsigned short* __restrict__ hbf,
                                                  const float4* __restrict__ cnt4,
                                                  const float* __restrict__ eb,
                                                  const float4* __restrict__ bias4,
                                                  float* __restrict__ out, int M) {
    __shared__ __align__(16) unsigned char smem[49152];
    unsigned short* Sreg = (unsigned short*)smem;            // 8KB; Xagg overlay
    unsigned short* Hbt  = (unsigned short*)(smem + 8192);   // 8KB
    unsigned short* Wreg = (unsigned short*)(smem + 16384);  // 32KB
    unsigned short* Xag  = Sreg;                             // overlay after phase A
    float* OutsF = (float*)(smem + 16384);                   // epilogue overlay

    const int tid = threadIdx.x;
    const int m0 = blockIdx.x * 32;
    const int lane = tid & 63, w = tid >> 6;   // w in 0..3
    const int lm = lane & 15, quad = lane >> 4;

    // ---- phase A: agg = S @ Wc^T, K=512, BK=128 ----
    floatx4 accA[2][2];
#pragma unroll
    for (int x = 0; x < 2; ++x)
#pragma unroll
        for (int y = 0; y < 2; ++y) accA[x][y] = (floatx4){0.f, 0.f, 0.f, 0.f};

#pragma unroll 1
    for (int c = 0; c < 4; ++c) {
        // DMA S c-slice -> Sreg (8KB = 8 chunks; wave w does 2)
#pragma unroll
        for (int i = 0; i < 2; ++i) {
            int k = w * 2 + i;
            int slot = k * 64 + lane;
            int row = slot >> 4, x = slot & 15;
            int grow = m0 + row; if (grow >= M) grow = M - 1;
            gload16(S + (size_t)grow * 512 + c * 128 + ((x ^ (row & 7)) << 3),
                    Sreg + k * 512);
        }
        // DMA Wc c-slice -> Wreg (32KB = 32 chunks; wave w does 8)
#pragma unroll
        for (int i = 0; i < 8; ++i) {
            int kk = w * 8 + i;
            int slot = kk * 64 + lane;
            int j = slot >> 4, x = slot & 15;
            gload16(Wc + (size_t)j * 512 + c * 128 + ((x ^ (j & 7)) << 3),
                    Wreg + kk * 512);
        }
        __syncthreads();   // drains DMA (vmcnt) + orders for all waves
#pragma unroll
        for (int ss = 0; ss < 4; ++ss) {
            int g = ss * 4 + quad;
            short8 av[2], bw[2];
#pragma unroll
            for (int mi = 0; mi < 2; ++mi)
                av[mi] = *(const short8*)&Sreg[(mi * 16 + lm) * 128 + ((g ^ (lm & 7)) << 3)];
#pragma unroll
            for (int ni = 0; ni < 2; ++ni)
                bw[ni] = *(const short8*)&Wreg[(w * 32 + ni * 16 + lm) * 128 + ((g ^ (lm & 7)) << 3)];
#pragma unroll
            for (int mi = 0; mi < 2; ++mi)
#pragma unroll
                for (int ni = 0; ni < 2; ++ni)
                    accA[mi][ni] = __builtin_amdgcn_mfma_f32_16x16x32_bf16(av[mi], bw[ni], accA[mi][ni], 0, 0, 0);
        }
        __syncthreads();   // WAR: next c overwrites Sreg/Wreg; last iter frees Sreg
    }

    // DMA Hbt (h tile, 8KB = 8 chunks; wave w does 2) -- independent region
#pragma unroll
    for (int i = 0; i < 2; ++i) {
        int k = w * 2 + i;
        int slot = k * 64 + lane;
        int row = slot >> 4, x = slot & 15;
        int grow = m0 + row; if (grow >= M) grow = M - 1;
        gload16(hbf + (size_t)grow * HID + ((x ^ (row & 7)) << 3),
                Hbt + k * 512);
    }

    // handoff: agg(+cnt.eb) -> Xagg (Sreg region; phase-A reads fenced)
    {
#pragma unroll
        for (int ni = 0; ni < 2; ++ni) {
            int j = w * 32 + ni * 16 + lm;
            float e0 = eb[j], e1 = eb[HID + j], e2 = eb[2 * HID + j], e3 = eb[3 * HID + j];
            int jg = j >> 3, jr = j & 7;
#pragma unroll
            for (int mi = 0; mi < 2; ++mi) {
#pragma unroll
                for (int r = 0; r < 4; ++r) {
                    int nl = mi * 16 + quad * 4 + r;          // 0..31
                    int gn = m0 + nl;
                    if (gn >= M) gn = M - 1;
                    float4 c4 = cnt4[gn];
                    float v = accA[mi][ni][r] + c4.x * e0 + c4.y * e1 + c4.z * e2 + c4.w * e3;
                    Xag[nl * 128 + ((jg ^ (nl & 7)) << 3) + jr] = f2bf(v);
                }
            }
        }
    }
    __syncthreads();  // Xagg + Hbt DMA visible to all waves

    // ---- phase B: 4 gate chunks x 2 kc halves ----
    float fin[4][2][2];

#pragma unroll 1
    for (int gc = 0; gc < 4; ++gc) {
        floatx4 acc2[2][2];
#pragma unroll
        for (int x = 0; x < 2; ++x)
#pragma unroll
            for (int y = 0; y < 2; ++y) acc2[x][y] = (floatx4){0.f, 0.f, 0.f, 0.f};

#pragma unroll 1
        for (int kc = 0; kc < 2; ++kc) {
            // DMA Wg chunk slice (32KB = 32 chunks; wave w does 8)
#pragma unroll
            for (int i = 0; i < 8; ++i) {
                int kk = w * 8 + i;
                int slot = kk * 64 + lane;
                int rr = slot >> 4, x = slot & 15;
                gload16(Wg + (size_t)(gc * 128 + rr) * 256 + kc * 128 + ((x ^ (rr & 7)) << 3),
                        Wreg + kk * 512);
            }
            __syncthreads();
            const unsigned short* Bsrc = kc ? Hbt : Xag;
#pragma unroll
            for (int ss = 0; ss < 4; ++ss) {
                int g = ss * 4 + quad;
                short8 af[2], bfr[2];
#pragma unroll
                for (int mi2 = 0; mi2 < 2; ++mi2)
                    af[mi2] = *(const short8*)&Wreg[(w * 32 + mi2 * 16 + lm) * 128 + ((g ^ (lm & 7)) << 3)];
#pragma unroll
                for (int ni = 0; ni < 2; ++ni)
                    bfr[ni] = *(const short8*)&Bsrc[(ni * 16 + lm) * 128 + ((g ^ (lm & 7)) << 3)];
#pragma unroll
                for (int mi2 = 0; mi2 < 2; ++mi2)
#pragma unroll
                    for (int ni = 0; ni < 2; ++ni)
                        acc2[mi2][ni] = __builtin_amdgcn_mfma_f32_16x16x32_bf16(af[mi2], bfr[ni], acc2[mi2][ni], 0, 0, 0);
            }
            __syncthreads();  // WAR before next Wg stage
        }

        // GRU math: gate row = gc*128 + w*32 + mi2*16 + quad*4 + g
        //   -> j = gc*32 + w*8 + mi2*4 + quad, gate g = reg index
#pragma unroll
        for (int mi2 = 0; mi2 < 2; ++mi2) {
            int j = gc * 32 + w * 8 + mi2 * 4 + quad;   // 0..127
            float4 bb = bias4[j];                       // {b_r,b_z,b_in,b_hn}
            int jg = j >> 3, jr = j & 7;
#pragma unroll
            for (int ni = 0; ni < 2; ++ni) {
                int nl = ni * 16 + lm;
                float g0 = acc2[mi2][ni][0], g1 = acc2[mi2][ni][1];
                float g2 = acc2[mi2][ni][2], g3 = acc2[mi2][ni][3];
                float rr = frcp(1.f + __expf(-(g0 + bb.x)));
                float zz = frcp(1.f + __expf(-(g1 + bb.y)));
                float aa = g2 + bb.z + rr * (g3 + bb.w);
                float nn = 1.f - 2.f * frcp(1.f + __expf(2.f * aa));  // tanh
                float hv = bf2f((unsigned int)Hbt[nl * 128 + ((jg ^ (nl & 7)) << 3) + jr]);
                fin[gc][mi2][ni] = nn + zz * (hv - nn);
            }
        }
    }
    __syncthreads();  // all Wreg/Hbt/Xag reads done -> Outs overlay safe

    // fin -> Outs (f32, swizzled: 4-float group gq at gq^(row&7))
#pragma unroll
    for (int gc = 0; gc < 4; ++gc) {
#pragma unroll
        for (int mi2 = 0; mi2 < 2; ++mi2) {
            int j = gc * 32 + w * 8 + mi2 * 4 + quad;
            int gq = j >> 2, jr = j & 3;
#pragma unroll
            for (int ni = 0; ni < 2; ++ni) {
                int nl = ni * 16 + lm;
                OutsF[nl * 128 + ((gq ^ (nl & 7)) << 2) + jr] = fin[gc][mi2][ni];
            }
        }
    }
    __syncthreads();

    // coalesced store: 32 nodes x 128 floats
    {
        int row = tid >> 3;              // 0..31
        int cb = (tid & 7) * 16;         // 0..112
        int node = m0 + row;
        if (node < M) {
            float* dstp = out + (size_t)node * HID + cb;
#pragma unroll
            for (int i = 0; i < 4; ++i) {
                int gq = (cb >> 2) + i;
                *(float4*)(dstp + i * 4) = *(const float4*)&OutsF[row * 128 + ((gq ^ (row & 7)) << 2)];
            }
        }
    }
}

// ---------------------------------------------------------------------------

extern "C" void kernel_launch(void* const* d_in, const int* in_sizes, int n_in,
                              void* d_out, int out_size, void* d_ws, size_t ws_size,
                              hipStream_t stream) {
    const float* node_states = (const float*)d_in[0];
    const int*   edge_index  = (const int*)d_in[1];
    const int*   edge_type   = (const int*)d_in[2];
    const float* edge_W      = (const float*)d_in[3];
    const float* edge_b      = (const float*)d_in[4];
    const float* w_ih        = (const float*)d_in[5];
    const float* w_hh        = (const float*)d_in[6];
    const float* b_ih        = (const float*)d_in[7];
    const float* b_hh        = (const float*)d_in[8];

    const int M = in_sizes[0] / HID;      // 50000 nodes
    const int E = in_sizes[1] / 2;        // 625000 edges
    const int N4 = M * 4;                 // 200000 (dst,type) segments
    const int* src = edge_index;
    const int* dst = edge_index + E;

    // workspace layout (~70 MB)
    char* ws = (char*)d_ws;
    size_t off = 0;
    unsigned short* hbf   = (unsigned short*)(ws + off); off += (size_t)M * HID * 2;    // 12.8MB
    float*          bias4 = (float*)(ws + off);          off += (size_t)128 * 4 * 4;    // 2KB
    unsigned short* S     = (unsigned short*)(ws + off); off += (size_t)M * 512 * 2;    // 51.2MB
    unsigned short* Wcat  = (unsigned short*)(ws + off); off += (size_t)128 * 512 * 2;  // 128KB
    unsigned short* Wgru  = (unsigned short*)(ws + off); off += (size_t)512 * 256 * 2;  // 256KB
    float*          cnt4  = (float*)(ws + off);          off += (size_t)M * 4 * 4;      // 800KB
    int* deg4     = (int*)(ws + off); off += (size_t)N4 * 4;
    int* rowptr4  = (int*)(ws + off); off += (size_t)(N4 + 1) * 4;
    int* cursor4  = (int*)(ws + off); off += (size_t)N4 * 4;
    int* blocksum = (int*)(ws + off); off += 256 * 4;
    int* blockoff = (int*)(ws + off); off += 256 * 4;
    int* csr      = (int*)(ws + off); off += (size_t)E * 4;

    const int total4 = M * HID / 4;
    const int nb_cvt = (total4 + 255) / 256;     // 6250
    const int nb_zero = (N4 + 255) / 256;        // 782
    const int nb_scan = (N4 + 1023) / 1024;      // 196 <= 256

    prep_kernel<<<nb_cvt + 769 + nb_zero, 256, 0, stream>>>(
        node_states, hbf, edge_W, Wcat, w_ih, w_hh, Wgru, bias4, b_ih, b_hh,
        deg4, total4, nb_cvt, N4);

    hist4_kernel<<<(E + 255) / 256, 256, 0, stream>>>(dst, edge_type, deg4, E);
    scan_blocks4_kernel<<<nb_scan, 256, 0, stream>>>(deg4, rowptr4, blocksum, N4);
    scan_top_kernel<<<1, 256, 0, stream>>>(blocksum, blockoff, nb_scan);
    finalize4_kernel<<<(N4 + 255) / 256, 256, 0, stream>>>(rowptr4, blockoff, cursor4, N4, E);
    fill4_kernel<<<(E + 255) / 256, 256, 0, stream>>>(src, dst, edge_type, cursor4, csr, E);

    gather_s_kernel<<<(M + 3) / 4, 256, 0, stream>>>(rowptr4, csr, (const unsigned int*)hbf,
                                                     (float4*)cnt4, (unsigned int*)S, M);

    agg_gru<<<(M + 31) / 32, 256, 0, stream>>>(S, Wcat, Wgru, hbf, (const float4*)cnt4,
                                               edge_b, (const float4*)bias4, (float*)d_out, M);
}

// Round 11
// 241.117 us; speedup vs baseline: 3.4001x; 1.0111x over previous
//
#include <hip/hip_runtime.h>

// ---------------------------------------------------------------------------
// GGNN message passing, MI355X/gfx950.  Round 20 = R19 + launch-count cut.
//   R19 post-mortem: DMA staging null (67->69us, conflicts UNCHANGED 5.2M ->
//   they were read-side all along).  Five agg_gru structural variants all
//   67-69us => agg_gru retired as near-structural-optimum (verbatim R19).
//   Hidden tier = 175us over 7 small dependent launches; bottom-up kernel
//   cost ~50-70us => launch overhead (~10us each) + drains dominate.
//   This round: 8 kernel launches -> 6 + 1 SDMA memset:
//     - deg4 zero -> hipMemsetAsync (DMA engine, graph-capturable)
//     - prep + hist fused (block-range split; independent work, one launch)
//     - scan_top + finalize fused (each finalize block re-scans the 196
//       blocksums locally -- no polling, no coop, R17-safe)
// Lessons: no gather-into-GEMM fusion (R6); no K-merging (R7); LDS-staged
// coalesced out stores (R5); (dst,type) CSR (R6/R9); watch WRITE_SIZE for
// spill (R12); weights must be LDS-staged (R16); NO cooperative kernels /
// grid.sync ~100us each (R14/R17); wave-per-node gather (R15); agg_gru
// tile/grid/staging retunes null at ~67us (R18/R19).
// ---------------------------------------------------------------------------

typedef __attribute__((ext_vector_type(8))) short short8;
typedef __attribute__((ext_vector_type(4))) float floatx4;

#define HID 128
#define NTY 4

__device__ __forceinline__ unsigned short f2bf(float f) {
    unsigned int u = __float_as_uint(f);
    unsigned int r = (u + 0x7fffu + ((u >> 16) & 1u)) >> 16;  // RNE
    return (unsigned short)r;
}
__device__ __forceinline__ float bf2f(unsigned int lo16) {
    return __uint_as_float(lo16 << 16);
}
__device__ __forceinline__ float frcp(float x) { return __builtin_amdgcn_rcpf(x); }

// 16B global->LDS DMA: per-lane global src, wave-uniform LDS base + lane*16.
__device__ __forceinline__ void gload16(const unsigned short* g, unsigned short* l) {
    __builtin_amdgcn_global_load_lds(
        (const __attribute__((address_space(1))) unsigned int*)g,
        (__attribute__((address_space(3))) unsigned int*)l,
        16, 0, 0);
}

// ---- prep_hist: cvt_h | pack_wcat | pack_wgru | bias4 | histogram ---------
// deg4 pre-zeroed by hipMemsetAsync.  All branches independent.

__global__ void prep_hist_kernel(const float* __restrict__ h, unsigned short* __restrict__ hbf,
                                 const float* __restrict__ W, unsigned short* __restrict__ Wc,
                                 const float* __restrict__ w_ih, const float* __restrict__ w_hh,
                                 unsigned short* __restrict__ Wg, float* __restrict__ bias4,
                                 const float* __restrict__ b_ih, const float* __restrict__ b_hh,
                                 const int* __restrict__ dst, const int* __restrict__ ety,
                                 int* __restrict__ deg4, int total4, int nb_cvt, int E) {
    int b = blockIdx.x, tt = threadIdx.x;
    if (b < nb_cvt) {
        int i = b * 256 + tt;
        if (i < total4) {
            float4 v = ((const float4*)h)[i];
            uint2 o;
            o.x = (unsigned int)f2bf(v.x) | ((unsigned int)f2bf(v.y) << 16);
            o.y = (unsigned int)f2bf(v.z) | ((unsigned int)f2bf(v.w) << 16);
            ((uint2*)hbf)[i] = o;
        }
    } else if (b < nb_cvt + 256) {
        // Wcat[j][t*128+k] = edge_W[t][j][k]  (128 x 512)
        int idx = (b - nb_cvt) * 256 + tt;
        int j = idx >> 9, rem = idx & 511;
        int t = rem >> 7, k = rem & 127;
        Wc[idx] = f2bf(W[(t * HID + j) * HID + k]);
    } else if (b < nb_cvt + 768) {
        // Wg[512][256]: rows 4j+{0,1,2,3} = r|z|i_n|h_n; cols 0-127 agg, 128-255 h
        int idx = (b - nb_cvt - 256) * 256 + tt;
        int row = idx >> 8, k = idx & 255;
        int j = row >> 2, g = row & 3;
        float v = 0.0f;
        if (g == 0) v = (k < 128) ? w_ih[j * 128 + k]         : w_hh[j * 128 + (k - 128)];
        else if (g == 1) v = (k < 128) ? w_ih[(128 + j) * 128 + k] : w_hh[(128 + j) * 128 + (k - 128)];
        else if (g == 2) v = (k < 128) ? w_ih[(256 + j) * 128 + k] : 0.0f;
        else             v = (k < 128) ? 0.0f : w_hh[(256 + j) * 128 + (k - 128)];
        Wg[idx] = f2bf(v);
    } else if (b == nb_cvt + 768) {
        if (tt < 128) {
            float4 v;
            v.x = b_ih[tt] + b_hh[tt];
            v.y = b_ih[128 + tt] + b_hh[128 + tt];
            v.z = b_ih[256 + tt];
            v.w = b_hh[256 + tt];
            ((float4*)bias4)[tt] = v;
        }
    } else {
        int e = (b - nb_cvt - 769) * 256 + tt;
        if (e < E) atomicAdd(&deg4[dst[e] * 4 + ety[e]], 1);
    }
}

// ---- per-1024-chunk exclusive scans (R6, verified) ------------------------

__global__ void scan_blocks4_kernel(const int* __restrict__ deg, int* __restrict__ rowptr,
                                    int* __restrict__ blocksum, int N4) {
    __shared__ int s[256];
    int t = threadIdx.x;
    int base = blockIdx.x * 1024 + t * 4;
    int v0 = 0, v1 = 0, v2 = 0, v3 = 0;
    if (base + 3 < N4) {
        v0 = deg[base]; v1 = deg[base + 1]; v2 = deg[base + 2]; v3 = deg[base + 3];
    } else {
        if (base < N4) v0 = deg[base];
        if (base + 1 < N4) v1 = deg[base + 1];
        if (base + 2 < N4) v2 = deg[base + 2];
    }
    int sum = v0 + v1 + v2 + v3;
    s[t] = sum;
    __syncthreads();
#pragma unroll
    for (int off = 1; off < 256; off <<= 1) {
        int x = (t >= off) ? s[t - off] : 0;
        __syncthreads();
        s[t] += x;
        __syncthreads();
    }
    int ex = s[t] - sum;
    if (base < N4) rowptr[base] = ex;
    if (base + 1 < N4) rowptr[base + 1] = ex + v0;
    if (base + 2 < N4) rowptr[base + 2] = ex + v0 + v1;
    if (base + 3 < N4) rowptr[base + 3] = ex + v0 + v1 + v2;
    if (t == 255) blocksum[blockIdx.x] = s[255];
}

// ---- finalize_top: each block re-scans the <=256 blocksums locally --------
// Replaces scan_top + finalize (one launch instead of two, no polling).

__global__ void finalize_top_kernel(const int* __restrict__ blocksum, int* __restrict__ rowptr,
                                    int* __restrict__ cursor, int N4, int E, int nb) {
    __shared__ int s[256];
    int t = threadIdx.x;
    int v = (t < nb) ? blocksum[t] : 0;
    s[t] = v;
    __syncthreads();
#pragma unroll
    for (int off = 1; off < 256; off <<= 1) {
        int x = (t >= off) ? s[t - off] : 0;
        __syncthreads();
        s[t] += x;
        __syncthreads();
    }
    // s[k] = inclusive prefix of blocksum; chunk c offset = (c==0)?0:s[c-1]
    int i = blockIdx.x * blockDim.x + t;
    if (i < N4) {
        int c = i >> 10;
        int off0 = (c == 0) ? 0 : s[c - 1];
        int r = rowptr[i] + off0;
        rowptr[i] = r;
        cursor[i] = r;
    }
    if (i == 0) rowptr[N4] = E;  // sentinel
}

__global__ void fill4_kernel(const int* __restrict__ src, const int* __restrict__ dst,
                             const int* __restrict__ ety, int* __restrict__ cursor,
                             int* __restrict__ csr, int E) {
    int e = blockIdx.x * blockDim.x + threadIdx.x;
    if (e >= E) return;
    int pos = atomicAdd(&cursor[dst[e] * 4 + ety[e]], 1);
    csr[pos] = src[e];
}

// ---- gather_s v4 (R13/R16, measured-best): flat MLP-8 + snapshots ---------

__global__ void gather_s_kernel(const int* __restrict__ rowptr4, const int* __restrict__ csr,
                                const unsigned int* __restrict__ hbu,
                                float4* __restrict__ cnt4, unsigned int* __restrict__ Su, int N) {
    int w = blockIdx.x * (blockDim.x >> 6) + (threadIdx.x >> 6);
    if (w >= N) return;
    int lane = threadIdx.x & 63;
    int b0 = __builtin_amdgcn_readfirstlane(rowptr4[w * 4]);
    int b1 = __builtin_amdgcn_readfirstlane(rowptr4[w * 4 + 1]);
    int b2 = __builtin_amdgcn_readfirstlane(rowptr4[w * 4 + 2]);
    int b3 = __builtin_amdgcn_readfirstlane(rowptr4[w * 4 + 3]);
    int b4 = __builtin_amdgcn_readfirstlane(rowptr4[w * 4 + 4]);  // sentinel-backed

    float s0 = 0.f, s1 = 0.f;
    float sn0[3], sn1[3];

    int e = b0;
    while (e + 8 <= b4) {
        int p[8];
        unsigned int u[8];
#pragma unroll
        for (int i = 0; i < 8; ++i) p[i] = csr[e + i];
#pragma unroll
        for (int i = 0; i < 8; ++i) u[i] = hbu[(size_t)p[i] * 64 + lane];
#pragma unroll
        for (int i = 0; i < 8; ++i) {
            int idx = e + i;
            if (idx == b1) { sn0[0] = s0; sn1[0] = s1; }
            if (idx == b2) { sn0[1] = s0; sn1[1] = s1; }
            if (idx == b3) { sn0[2] = s0; sn1[2] = s1; }
            s0 += bf2f(u[i] & 0xffffu);
            s1 += bf2f(u[i] >> 16);
        }
        e += 8;
    }
    {   // tail: 0..7 edges, uniform predication
        int rem = b4 - e;
        int p[7];
        unsigned int u[7];
#pragma unroll
        for (int i = 0; i < 7; ++i) if (i < rem) p[i] = csr[e + i];
#pragma unroll
        for (int i = 0; i < 7; ++i) if (i < rem) u[i] = hbu[(size_t)p[i] * 64 + lane];
#pragma unroll
        for (int i = 0; i < 7; ++i) {
            if (i < rem) {
                int idx = e + i;
                if (idx == b1) { sn0[0] = s0; sn1[0] = s1; }
                if (idx == b2) { sn0[1] = s0; sn1[1] = s1; }
                if (idx == b3) { sn0[2] = s0; sn1[2] = s1; }
                s0 += bf2f(u[i] & 0xffffu);
                s1 += bf2f(u[i] >> 16);
            }
        }
    }
    if (b1 == b4) { sn0[0] = s0; sn1[0] = s1; }
    if (b2 == b4) { sn0[1] = s0; sn1[1] = s1; }
    if (b3 == b4) { sn0[2] = s0; sn1[2] = s1; }

    size_t base = (size_t)w * 256 + lane;
    float a0, a1, p0 = 0.f, p1 = 0.f;
#pragma unroll
    for (int t = 0; t < 4; ++t) {
        float c0 = (t < 3) ? sn0[t] : s0;
        float c1 = (t < 3) ? sn1[t] : s1;
        a0 = c0 - p0; a1 = c1 - p1;
        p0 = c0; p1 = c1;
        Su[base + t * 64] = (unsigned int)f2bf(a0) | ((unsigned int)f2bf(a1) << 16);
    }
    if (lane == 0)
        cnt4[w] = make_float4((float)(b1 - b0), (float)(b2 - b1),
                              (float)(b3 - b2), (float)(b4 - b3));
}

// ---- agg_gru v8 (verbatim R19, passed @69us): DMA-staged fused GEMM->GRU --
// 32-node tile, 256 threads (4 waves), 48KB LDS:
//   Sreg/Xagg overlay @0 (8KB) | Hbt @8192 (8KB) | Wreg @16384 (32KB);
//   OutsF (16KB) overlays Wreg in the epilogue.
// Staging = gload16 DMA: LDS linear, global source INVERSE-swizzled
// (LDS[row][x] = global[row][x^(row&7)]); reads XOR (both-sides pattern).

__global__ __launch_bounds__(256, 3) void agg_gru(const unsigned short* __restrict__ S,
                                                  const unsigned short* __restrict__ Wc,
                                                  const unsigned short* __restrict__ Wg,
                                                  const unsigned short* __restrict__ hbf,
                                                  const float4* __restrict__ cnt4,
                                                  const float* __restrict__ eb,
                                                  const float4* __restrict__ bias4,
                                                  float* __restrict__ out, int M) {
    __shared__ __align__(16) unsigned char smem[49152];
    unsigned short* Sreg = (unsigned short*)smem;            // 8KB; Xagg overlay
    unsigned short* Hbt  = (unsigned short*)(smem + 8192);   // 8KB
    unsigned short* Wreg = (unsigned short*)(smem + 16384);  // 32KB
    unsigned short* Xag  = Sreg;                             // overlay after phase A
    float* OutsF = (float*)(smem + 16384);                   // epilogue overlay

    const int tid = threadIdx.x;
    const int m0 = blockIdx.x * 32;
    const int lane = tid & 63, w = tid >> 6;   // w in 0..3
    const int lm = lane & 15, quad = lane >> 4;

    // ---- phase A: agg = S @ Wc^T, K=512, BK=128 ----
    floatx4 accA[2][2];
#pragma unroll
    for (int x = 0; x < 2; ++x)
#pragma unroll
        for (int y = 0; y < 2; ++y) accA[x][y] = (floatx4){0.f, 0.f, 0.f, 0.f};

#pragma unroll 1
    for (int c = 0; c < 4; ++c) {
        // DMA S c-slice -> Sreg (8KB = 8 chunks; wave w does 2)
#pragma unroll
        for (int i = 0; i < 2; ++i) {
            int k = w * 2 + i;
            int slot = k * 64 + lane;
            int row = slot >> 4, x = slot & 15;
            int grow = m0 + row; if (grow >= M) grow = M - 1;
            gload16(S + (size_t)grow * 512 + c * 128 + ((x ^ (row & 7)) << 3),
                    Sreg + k * 512);
        }
        // DMA Wc c-slice -> Wreg (32KB = 32 chunks; wave w does 8)
#pragma unroll
        for (int i = 0; i < 8; ++i) {
            int kk = w * 8 + i;
            int slot = kk * 64 + lane;
            int j = slot >> 4, x = slot & 15;
            gload16(Wc + (size_t)j * 512 + c * 128 + ((x ^ (j & 7)) << 3),
                    Wreg + kk * 512);
        }
        __syncthreads();   // drains DMA (vmcnt) + orders for all waves
#pragma unroll
        for (int ss = 0; ss < 4; ++ss) {
            int g = ss * 4 + quad;
            short8 av[2], bw[2];
#pragma unroll
            for (int mi = 0; mi < 2; ++mi)
                av[mi] = *(const short8*)&Sreg[(mi * 16 + lm) * 128 + ((g ^ (lm & 7)) << 3)];
#pragma unroll
            for (int ni = 0; ni < 2; ++ni)
                bw[ni] = *(const short8*)&Wreg[(w * 32 + ni * 16 + lm) * 128 + ((g ^ (lm & 7)) << 3)];
#pragma unroll
            for (int mi = 0; mi < 2; ++mi)
#pragma unroll
                for (int ni = 0; ni < 2; ++ni)
                    accA[mi][ni] = __builtin_amdgcn_mfma_f32_16x16x32_bf16(av[mi], bw[ni], accA[mi][ni], 0, 0, 0);
        }
        __syncthreads();   // WAR: next c overwrites Sreg/Wreg; last iter frees Sreg
    }

    // DMA Hbt (h tile, 8KB = 8 chunks; wave w does 2) -- independent region
#pragma unroll
    for (int i = 0; i < 2; ++i) {
        int k = w * 2 + i;
        int slot = k * 64 + lane;
        int row = slot >> 4, x = slot & 15;
        int grow = m0 + row; if (grow >= M) grow = M - 1;
        gload16(hbf + (size_t)grow * HID + ((x ^ (row & 7)) << 3),
                Hbt + k * 512);
    }

    // handoff: agg(+cnt.eb) -> Xagg (Sreg region; phase-A reads fenced)
    {
#pragma unroll
        for (int ni = 0; ni < 2; ++ni) {
            int j = w * 32 + ni * 16 + lm;
            float e0 = eb[j], e1 = eb[HID + j], e2 = eb[2 * HID + j], e3 = eb[3 * HID + j];
            int jg = j >> 3, jr = j & 7;
#pragma unroll
            for (int mi = 0; mi < 2; ++mi) {
#pragma unroll
                for (int r = 0; r < 4; ++r) {
                    int nl = mi * 16 + quad * 4 + r;          // 0..31
                    int gn = m0 + nl;
                    if (gn >= M) gn = M - 1;
                    float4 c4 = cnt4[gn];
                    float v = accA[mi][ni][r] + c4.x * e0 + c4.y * e1 + c4.z * e2 + c4.w * e3;
                    Xag[nl * 128 + ((jg ^ (nl & 7)) << 3) + jr] = f2bf(v);
                }
            }
        }
    }
    __syncthreads();  // Xagg + Hbt DMA visible to all waves

    // ---- phase B: 4 gate chunks x 2 kc halves ----
    float fin[4][2][2];

#pragma unroll 1
    for (int gc = 0; gc < 4; ++gc) {
        floatx4 acc2[2][2];
#pragma unroll
        for (int x = 0; x < 2; ++x)
#pragma unroll
            for (int y = 0; y < 2; ++y) acc2[x][y] = (floatx4){0.f, 0.f, 0.f, 0.f};

#pragma unroll 1
        for (int kc = 0; kc < 2; ++kc) {
            // DMA Wg chunk slice (32KB = 32 chunks; wave w does 8)
#pragma unroll
            for (int i = 0; i < 8; ++i) {
                int kk = w * 8 + i;
                int slot = kk * 64 + lane;
                int rr = slot >> 4, x = slot & 15;
                gload16(Wg + (size_t)(gc * 128 + rr) * 256 + kc * 128 + ((x ^ (rr & 7)) << 3),
                        Wreg + kk * 512);
            }
            __syncthreads();
            const unsigned short* Bsrc = kc ? Hbt : Xag;
#pragma unroll
            for (int ss = 0; ss < 4; ++ss) {
                int g = ss * 4 + quad;
                short8 af[2], bfr[2];
#pragma unroll
                for (int mi2 = 0; mi2 < 2; ++mi2)
                    af[mi2] = *(const short8*)&Wreg[(w * 32 + mi2 * 16 + lm) * 128 + ((g ^ (lm & 7)) << 3)];
#pragma unroll
                for (int ni = 0; ni < 2; ++ni)
                    bfr[ni] = *(const short8*)&Bsrc[(ni * 16 + lm) * 128 + ((g ^ (lm & 7)) << 3)];
#pragma unroll
                for (int mi2 = 0; mi2 < 2; ++mi2)
#pragma unroll
                    for (int ni = 0; ni < 2; ++ni)
                        acc2[mi2][ni] = __builtin_amdgcn_mfma_f32_16x16x32_bf16(af[mi2], bfr[ni], acc2[mi2][ni], 0, 0, 0);
            }
            __syncthreads();  // WAR before next Wg stage
        }

        // GRU math: gate row = gc*128 + w*32 + mi2*16 + quad*4 + g
        //   -> j = gc*32 + w*8 + mi2*4 + quad, gate g = reg index
#pragma unroll
        for (int mi2 = 0; mi2 < 2; ++mi2) {
            int j = gc * 32 + w * 8 + mi2 * 4 + quad;   // 0..127
            float4 bb = bias4[j];                       // {b_r,b_z,b_in,b_hn}
            int jg = j >> 3, jr = j & 7;
#pragma unroll
            for (int ni = 0; ni < 2; ++ni) {
                int nl = ni * 16 + lm;
                float g0 = acc2[mi2][ni][0], g1 = acc2[mi2][ni][1];
                float g2 = acc2[mi2][ni][2], g3 = acc2[mi2][ni][3];
                float rr = frcp(1.f + __expf(-(g0 + bb.x)));
                float zz = frcp(1.f + __expf(-(g1 + bb.y)));
                float aa = g2 + bb.z + rr * (g3 + bb.w);
                float nn = 1.f - 2.f * frcp(1.f + __expf(2.f * aa));  // tanh
                float hv = bf2f((unsigned int)Hbt[nl * 128 + ((jg ^ (nl & 7)) << 3) + jr]);
                fin[gc][mi2][ni] = nn + zz * (hv - nn);
            }
        }
    }
    __syncthreads();  // all Wreg/Hbt/Xag reads done -> Outs overlay safe

    // fin -> Outs (f32, swizzled: 4-float group gq at gq^(row&7))
#pragma unroll
    for (int gc = 0; gc < 4; ++gc) {
#pragma unroll
        for (int mi2 = 0; mi2 < 2; ++mi2) {
            int j = gc * 32 + w * 8 + mi2 * 4 + quad;
            int gq = j >> 2, jr = j & 3;
#pragma unroll
            for (int ni = 0; ni < 2; ++ni) {
                int nl = ni * 16 + lm;
                OutsF[nl * 128 + ((gq ^ (nl & 7)) << 2) + jr] = fin[gc][mi2][ni];
            }
        }
    }
    __syncthreads();

    // coalesced store: 32 nodes x 128 floats
    {
        int row = tid >> 3;              // 0..31
        int cb = (tid & 7) * 16;         // 0..112
        int node = m0 + row;
        if (node < M) {
            float* dstp = out + (size_t)node * HID + cb;
#pragma unroll
            for (int i = 0; i < 4; ++i) {
                int gq = (cb >> 2) + i;
                *(float4*)(dstp + i * 4) = *(const float4*)&OutsF[row * 128 + ((gq ^ (row & 7)) << 2)];
            }
        }
    }
}

// ---------------------------------------------------------------------------

extern "C" void kernel_launch(void* const* d_in, const int* in_sizes, int n_in,
                              void* d_out, int out_size, void* d_ws, size_t ws_size,
                              hipStream_t stream) {
    const float* node_states = (const float*)d_in[0];
    const int*   edge_index  = (const int*)d_in[1];
    const int*   edge_type   = (const int*)d_in[2];
    const float* edge_W      = (const float*)d_in[3];
    const float* edge_b      = (const float*)d_in[4];
    const float* w_ih        = (const float*)d_in[5];
    const float* w_hh        = (const float*)d_in[6];
    const float* b_ih        = (const float*)d_in[7];
    const float* b_hh        = (const float*)d_in[8];

    const int M = in_sizes[0] / HID;      // 50000 nodes
    const int E = in_sizes[1] / 2;        // 625000 edges
    const int N4 = M * 4;                 // 200000 (dst,type) segments
    const int* src = edge_index;
    const int* dst = edge_index + E;

    // workspace layout (~70 MB)
    char* ws = (char*)d_ws;
    size_t off = 0;
    unsigned short* hbf   = (unsigned short*)(ws + off); off += (size_t)M * HID * 2;    // 12.8MB
    float*          bias4 = (float*)(ws + off);          off += (size_t)128 * 4 * 4;    // 2KB
    unsigned short* S     = (unsigned short*)(ws + off); off += (size_t)M * 512 * 2;    // 51.2MB
    unsigned short* Wcat  = (unsigned short*)(ws + off); off += (size_t)128 * 512 * 2;  // 128KB
    unsigned short* Wgru  = (unsigned short*)(ws + off); off += (size_t)512 * 256 * 2;  // 256KB
    float*          cnt4  = (float*)(ws + off);          off += (size_t)M * 4 * 4;      // 800KB
    int* deg4     = (int*)(ws + off); off += (size_t)N4 * 4;
    int* rowptr4  = (int*)(ws + off); off += (size_t)(N4 + 1) * 4;
    int* cursor4  = (int*)(ws + off); off += (size_t)N4 * 4;
    int* blocksum = (int*)(ws + off); off += 256 * 4;
    int* csr      = (int*)(ws + off); off += (size_t)E * 4;

    const int total4 = M * HID / 4;
    const int nb_cvt = (total4 + 255) / 256;     // 6250
    const int nb_hist = (E + 255) / 256;         // 2442
    const int nb_scan = (N4 + 1023) / 1024;      // 196 <= 256

    // deg4 zero via SDMA (graph-capturable, overlaps launch setup)
    hipMemsetAsync(deg4, 0, (size_t)N4 * 4, stream);

    prep_hist_kernel<<<nb_cvt + 769 + nb_hist, 256, 0, stream>>>(
        node_states, hbf, edge_W, Wcat, w_ih, w_hh, Wgru, bias4, b_ih, b_hh,
        dst, edge_type, deg4, total4, nb_cvt, E);

    scan_blocks4_kernel<<<nb_scan, 256, 0, stream>>>(deg4, rowptr4, blocksum, N4);

    finalize_top_kernel<<<(N4 + 255) / 256, 256, 0, stream>>>(blocksum, rowptr4, cursor4,
                                                              N4, E, nb_scan);

    fill4_kernel<<<(E + 255) / 256, 256, 0, stream>>>(src, dst, edge_type, cursor4, csr, E);

    gather_s_kernel<<<(M + 3) / 4, 256, 0, stream>>>(rowptr4, csr, (const unsigned int*)hbf,
                                                     (float4*)cnt4, (unsigned int*)S, M);

    agg_gru<<<(M + 31) / 32, 256, 0, stream>>>(S, Wcat, Wgru, hbf, (const float4*)cnt4,
                                               edge_b, (const float4*)bias4, (float*)d_out, M);
}

// Round 12
// 234.919 us; speedup vs baseline: 3.4898x; 1.0264x over previous
//
#include <hip/hip_runtime.h>

// ---------------------------------------------------------------------------
// GGNN message passing, MI355X/gfx950.  Round 21 = R20 + single-pass CSR.
//   R20 post-mortem: launch-count cut bought 2.7us -> launches are graph-
//   replayed, hidden tier (178us) is EXECUTION-bound.  The CSR build made
//   3 passes over edges (hist+fill) + 2 scan kernels solely to compute slot
//   offsets that an atomic cursor computes alone.
//   This round: fixed-slot bucket fill (CAP=16/segment, avg occupancy 3.1,
//   P(ovf)~4e-8/seg) + correctness-preserving overflow list.  Deletes hist,
//   scan_blocks, finalize_top (one edge pass + 2 kernels + ~10MB traffic).
//   Chain: memset -> prep_fill -> gather -> agg_gru (4 ops).
//   gather: per-segment counts direct from cnti (no snapshots), ONE
//   predicated 16-deep round per segment (MLP 16).  S layout + cnt4
//   semantics + agg_gru (63us control) byte-identical to R20.
// Lessons: no gather-into-GEMM fusion (R6); no K-merging (R7); LDS-staged
// coalesced out stores (R5); watch WRITE_SIZE for spill (R12); weights must
// be LDS-staged (R16); NO cooperative kernels / grid.sync ~100us (R14/R17);
// wave-per-node gather (R15); agg_gru retunes null at ~65us (R18/R19);
// launch overhead negligible under graph replay (R20).
// ---------------------------------------------------------------------------

typedef __attribute__((ext_vector_type(8))) short short8;
typedef __attribute__((ext_vector_type(4))) float floatx4;

#define HID 128
#define NTY 4
#define CAP 16
#define OVF_MAX 65536

__device__ __forceinline__ unsigned short f2bf(float f) {
    unsigned int u = __float_as_uint(f);
    unsigned int r = (u + 0x7fffu + ((u >> 16) & 1u)) >> 16;  // RNE
    return (unsigned short)r;
}
__device__ __forceinline__ float bf2f(unsigned int lo16) {
    return __uint_as_float(lo16 << 16);
}
__device__ __forceinline__ float frcp(float x) { return __builtin_amdgcn_rcpf(x); }

// 16B global->LDS DMA: per-lane global src, wave-uniform LDS base + lane*16.
__device__ __forceinline__ void gload16(const unsigned short* g, unsigned short* l) {
    __builtin_amdgcn_global_load_lds(
        (const __attribute__((address_space(1))) unsigned int*)g,
        (__attribute__((address_space(3))) unsigned int*)l,
        16, 0, 0);
}

// ---- prep_fill: cvt_h | pack_wcat | pack_wgru | bias4 | bucket-fill -------
// cnti + ovfn pre-zeroed by hipMemsetAsync.  All branches independent.

__global__ void prep_fill_kernel(const float* __restrict__ h, unsigned short* __restrict__ hbf,
                                 const float* __restrict__ W, unsigned short* __restrict__ Wc,
                                 const float* __restrict__ w_ih, const float* __restrict__ w_hh,
                                 unsigned short* __restrict__ Wg, float* __restrict__ bias4,
                                 const float* __restrict__ b_ih, const float* __restrict__ b_hh,
                                 const int* __restrict__ src, const int* __restrict__ dst,
                                 const int* __restrict__ ety,
                                 int* __restrict__ cnti, int* __restrict__ csrF,
                                 int* __restrict__ ovfn, int2* __restrict__ ovf,
                                 int total4, int nb_cvt, int E) {
    int b = blockIdx.x, tt = threadIdx.x;
    if (b < nb_cvt) {
        int i = b * 256 + tt;
        if (i < total4) {
            float4 v = ((const float4*)h)[i];
            uint2 o;
            o.x = (unsigned int)f2bf(v.x) | ((unsigned int)f2bf(v.y) << 16);
            o.y = (unsigned int)f2bf(v.z) | ((unsigned int)f2bf(v.w) << 16);
            ((uint2*)hbf)[i] = o;
        }
    } else if (b < nb_cvt + 256) {
        // Wcat[j][t*128+k] = edge_W[t][j][k]  (128 x 512)
        int idx = (b - nb_cvt) * 256 + tt;
        int j = idx >> 9, rem = idx & 511;
        int t = rem >> 7, k = rem & 127;
        Wc[idx] = f2bf(W[(t * HID + j) * HID + k]);
    } else if (b < nb_cvt + 768) {
        // Wg[512][256]: rows 4j+{0,1,2,3} = r|z|i_n|h_n; cols 0-127 agg, 128-255 h
        int idx = (b - nb_cvt - 256) * 256 + tt;
        int row = idx >> 8, k = idx & 255;
        int j = row >> 2, g = row & 3;
        float v = 0.0f;
        if (g == 0) v = (k < 128) ? w_ih[j * 128 + k]         : w_hh[j * 128 + (k - 128)];
        else if (g == 1) v = (k < 128) ? w_ih[(128 + j) * 128 + k] : w_hh[(128 + j) * 128 + (k - 128)];
        else if (g == 2) v = (k < 128) ? w_ih[(256 + j) * 128 + k] : 0.0f;
        else             v = (k < 128) ? 0.0f : w_hh[(256 + j) * 128 + (k - 128)];
        Wg[idx] = f2bf(v);
    } else if (b == nb_cvt + 768) {
        if (tt < 128) {
            float4 v;
            v.x = b_ih[tt] + b_hh[tt];
            v.y = b_ih[128 + tt] + b_hh[128 + tt];
            v.z = b_ih[256 + tt];
            v.w = b_hh[256 + tt];
            ((float4*)bias4)[tt] = v;
        }
    } else {
        int e = (b - nb_cvt - 769) * 256 + tt;
        if (e < E) {
            int seg = dst[e] * 4 + ety[e];
            int pos = atomicAdd(&cnti[seg], 1);
            if (pos < CAP) {
                csrF[(size_t)seg * CAP + pos] = src[e];
            } else {
                int op = atomicAdd(ovfn, 1);
                if (op < OVF_MAX) ovf[op] = make_int2(seg, src[e]);
            }
        }
    }
}

// ---- gather_fixed: wave per node; per-segment predicated 16-round ---------
// Lane owns cols {2l,2l+1}.  Su[seg*64+lane] (== node*256+t*64+lane, same
// layout as R20).  cnt4f[node] = total per-type counts (incl. overflow).

__global__ void gather_fixed_kernel(const int* __restrict__ cnti, const int* __restrict__ csrF,
                                    const unsigned int* __restrict__ hbu,
                                    const int* __restrict__ ovfn, const int2* __restrict__ ovf,
                                    float4* __restrict__ cnt4f, unsigned int* __restrict__ Su, int N) {
    int w = blockIdx.x * (blockDim.x >> 6) + (threadIdx.x >> 6);
    if (w >= N) return;
    int lane = threadIdx.x & 63;

    int tot[4];
#pragma unroll
    for (int t = 0; t < 4; ++t)
        tot[t] = __builtin_amdgcn_readfirstlane(cnti[w * 4 + t]);

#pragma unroll 2
    for (int t = 0; t < 4; ++t) {
        int seg = w * 4 + t;
        int c = (tot[t] < CAP) ? tot[t] : CAP;
        int p[CAP];
        unsigned int u[CAP];
#pragma unroll
        for (int i = 0; i < CAP; ++i) if (i < c) p[i] = csrF[(size_t)seg * CAP + i];
#pragma unroll
        for (int i = 0; i < CAP; ++i) if (i < c) u[i] = hbu[(size_t)p[i] * 64 + lane];
        float s0 = 0.f, s1 = 0.f;
#pragma unroll
        for (int i = 0; i < CAP; ++i) {
            if (i < c) {
                s0 += bf2f(u[i] & 0xffffu);
                s1 += bf2f(u[i] >> 16);
            }
        }
        if (tot[t] > CAP) {   // rare: walk overflow list (correctness path)
            int on = __builtin_amdgcn_readfirstlane(ovfn[0]);
            if (on > OVF_MAX) on = OVF_MAX;
            for (int k = 0; k < on; ++k) {
                int2 oe = ovf[k];
                if (oe.x == seg) {
                    unsigned int uu = hbu[(size_t)oe.y * 64 + lane];
                    s0 += bf2f(uu & 0xffffu);
                    s1 += bf2f(uu >> 16);
                }
            }
        }
        Su[(size_t)seg * 64 + lane] = (unsigned int)f2bf(s0) | ((unsigned int)f2bf(s1) << 16);
    }
    if (lane == 0)
        cnt4f[w] = make_float4((float)tot[0], (float)tot[1], (float)tot[2], (float)tot[3]);
}

// ---- agg_gru v8 (verbatim R19/R20, 63us control): DMA-staged GEMM->GRU ----
// 32-node tile, 256 threads (4 waves), 48KB LDS:
//   Sreg/Xagg overlay @0 (8KB) | Hbt @8192 (8KB) | Wreg @16384 (32KB);
//   OutsF (16KB) overlays Wreg in the epilogue.
// Staging = gload16 DMA: LDS linear, global source INVERSE-swizzled
// (LDS[row][x] = global[row][x^(row&7)]); reads XOR (both-sides pattern).

__global__ __launch_bounds__(256, 3) void agg_gru(const unsigned short* __restrict__ S,
                                                  const unsigned short* __restrict__ Wc,
                                                  const unsigned short* __restrict__ Wg,
                                                  const unsigned short* __restrict__ hbf,
                                                  const float4* __restrict__ cnt4,
                                                  const float* __restrict__ eb,
                                                  const float4* __restrict__ bias4,
                                                  float* __restrict__ out, int M) {
    __shared__ __align__(16) unsigned char smem[49152];
    unsigned short* Sreg = (unsigned short*)smem;            // 8KB; Xagg overlay
    unsigned short* Hbt  = (unsigned short*)(smem + 8192);   // 8KB
    unsigned short* Wreg = (unsigned short*)(smem + 16384);  // 32KB
    unsigned short* Xag  = Sreg;                             // overlay after phase A
    float* OutsF = (float*)(smem + 16384);                   // epilogue overlay

    const int tid = threadIdx.x;
    const int m0 = blockIdx.x * 32;
    const int lane = tid & 63, w = tid >> 6;   // w in 0..3
    const int lm = lane & 15, quad = lane >> 4;

    // ---- phase A: agg = S @ Wc^T, K=512, BK=128 ----
    floatx4 accA[2][2];
#pragma unroll
    for (int x = 0; x < 2; ++x)
#pragma unroll
        for (int y = 0; y < 2; ++y) accA[x][y] = (floatx4){0.f, 0.f, 0.f, 0.f};

#pragma unroll 1
    for (int c = 0; c < 4; ++c) {
        // DMA S c-slice -> Sreg (8KB = 8 chunks; wave w does 2)
#pragma unroll
        for (int i = 0; i < 2; ++i) {
            int k = w * 2 + i;
            int slot = k * 64 + lane;
            int row = slot >> 4, x = slot & 15;
            int grow = m0 + row; if (grow >= M) grow = M - 1;
            gload16(S + (size_t)grow * 512 + c * 128 + ((x ^ (row & 7)) << 3),
                    Sreg + k * 512);
        }
        // DMA Wc c-slice -> Wreg (32KB = 32 chunks; wave w does 8)
#pragma unroll
        for (int i = 0; i < 8; ++i) {
            int kk = w * 8 + i;
            int slot = kk * 64 + lane;
            int j = slot >> 4, x = slot & 15;
            gload16(Wc + (size_t)j * 512 + c * 128 + ((x ^ (j & 7)) << 3),
                    Wreg + kk * 512);
        }
        __syncthreads();   // drains DMA (vmcnt) + orders for all waves
#pragma unroll
        for (int ss = 0; ss < 4; ++ss) {
            int g = ss * 4 + quad;
            short8 av[2], bw[2];
#pragma unroll
            for (int mi = 0; mi < 2; ++mi)
                av[mi] = *(const short8*)&Sreg[(mi * 16 + lm) * 128 + ((g ^ (lm & 7)) << 3)];
#pragma unroll
            for (int ni = 0; ni < 2; ++ni)
                bw[ni] = *(const short8*)&Wreg[(w * 32 + ni * 16 + lm) * 128 + ((g ^ (lm & 7)) << 3)];
#pragma unroll
            for (int mi = 0; mi < 2; ++mi)
#pragma unroll
                for (int ni = 0; ni < 2; ++ni)
                    accA[mi][ni] = __builtin_amdgcn_mfma_f32_16x16x32_bf16(av[mi], bw[ni], accA[mi][ni], 0, 0, 0);
        }
        __syncthreads();   // WAR: next c overwrites Sreg/Wreg; last iter frees Sreg
    }

    // DMA Hbt (h tile, 8KB = 8 chunks; wave w does 2) -- independent region
#pragma unroll
    for (int i = 0; i < 2; ++i) {
        int k = w * 2 + i;
        int slot = k * 64 + lane;
        int row = slot >> 4, x = slot & 15;
        int grow = m0 + row; if (grow >= M) grow = M - 1;
        gload16(hbf + (size_t)grow * HID + ((x ^ (row & 7)) << 3),
                Hbt + k * 512);
    }

    // handoff: agg(+cnt.eb) -> Xagg (Sreg region; phase-A reads fenced)
    {
#pragma unroll
        for (int ni = 0; ni < 2; ++ni) {
            int j = w * 32 + ni * 16 + lm;
            float e0 = eb[j], e1 = eb[HID + j], e2 = eb[2 * HID + j], e3 = eb[3 * HID + j];
            int jg = j >> 3, jr = j & 7;
#pragma unroll
            for (int mi = 0; mi < 2; ++mi) {
#pragma unroll
                for (int r = 0; r < 4; ++r) {
                    int nl = mi * 16 + quad * 4 + r;          // 0..31
                    int gn = m0 + nl;
                    if (gn >= M) gn = M - 1;
                    float4 c4 = cnt4[gn];
                    float v = accA[mi][ni][r] + c4.x * e0 + c4.y * e1 + c4.z * e2 + c4.w * e3;
                    Xag[nl * 128 + ((jg ^ (nl & 7)) << 3) + jr] = f2bf(v);
                }
            }
        }
    }
    __syncthreads();  // Xagg + Hbt DMA visible to all waves

    // ---- phase B: 4 gate chunks x 2 kc halves ----
    float fin[4][2][2];

#pragma unroll 1
    for (int gc = 0; gc < 4; ++gc) {
        floatx4 acc2[2][2];
#pragma unroll
        for (int x = 0; x < 2; ++x)
#pragma unroll
            for (int y = 0; y < 2; ++y) acc2[x][y] = (floatx4){0.f, 0.f, 0.f, 0.f};

#pragma unroll 1
        for (int kc = 0; kc < 2; ++kc) {
            // DMA Wg chunk slice (32KB = 32 chunks; wave w does 8)
#pragma unroll
            for (int i = 0; i < 8; ++i) {
                int kk = w * 8 + i;
                int slot = kk * 64 + lane;
                int rr = slot >> 4, x = slot & 15;
                gload16(Wg + (size_t)(gc * 128 + rr) * 256 + kc * 128 + ((x ^ (rr & 7)) << 3),
                        Wreg + kk * 512);
            }
            __syncthreads();
            const unsigned short* Bsrc = kc ? Hbt : Xag;
#pragma unroll
            for (int ss = 0; ss < 4; ++ss) {
                int g = ss * 4 + quad;
                short8 af[2], bfr[2];
#pragma unroll
                for (int mi2 = 0; mi2 < 2; ++mi2)
                    af[mi2] = *(const short8*)&Wreg[(w * 32 + mi2 * 16 + lm) * 128 + ((g ^ (lm & 7)) << 3)];
#pragma unroll
                for (int ni = 0; ni < 2; ++ni)
                    bfr[ni] = *(const short8*)&Bsrc[(ni * 16 + lm) * 128 + ((g ^ (lm & 7)) << 3)];
#pragma unroll
                for (int mi2 = 0; mi2 < 2; ++mi2)
#pragma unroll
                    for (int ni = 0; ni < 2; ++ni)
                        acc2[mi2][ni] = __builtin_amdgcn_mfma_f32_16x16x32_bf16(af[mi2], bfr[ni], acc2[mi2][ni], 0, 0, 0);
            }
            __syncthreads();  // WAR before next Wg stage
        }

        // GRU math: gate row = gc*128 + w*32 + mi2*16 + quad*4 + g
        //   -> j = gc*32 + w*8 + mi2*4 + quad, gate g = reg index
#pragma unroll
        for (int mi2 = 0; mi2 < 2; ++mi2) {
            int j = gc * 32 + w * 8 + mi2 * 4 + quad;   // 0..127
            float4 bb = bias4[j];                       // {b_r,b_z,b_in,b_hn}
            int jg = j >> 3, jr = j & 7;
#pragma unroll
            for (int ni = 0; ni < 2; ++ni) {
                int nl = ni * 16 + lm;
                float g0 = acc2[mi2][ni][0], g1 = acc2[mi2][ni][1];
                float g2 = acc2[mi2][ni][2], g3 = acc2[mi2][ni][3];
                float rr = frcp(1.f + __expf(-(g0 + bb.x)));
                float zz = frcp(1.f + __expf(-(g1 + bb.y)));
                float aa = g2 + bb.z + rr * (g3 + bb.w);
                float nn = 1.f - 2.f * frcp(1.f + __expf(2.f * aa));  // tanh
                float hv = bf2f((unsigned int)Hbt[nl * 128 + ((jg ^ (nl & 7)) << 3) + jr]);
                fin[gc][mi2][ni] = nn + zz * (hv - nn);
            }
        }
    }
    __syncthreads();  // all Wreg/Hbt/Xag reads done -> Outs overlay safe

    // fin -> Outs (f32, swizzled: 4-float group gq at gq^(row&7))
#pragma unroll
    for (int gc = 0; gc < 4; ++gc) {
#pragma unroll
        for (int mi2 = 0; mi2 < 2; ++mi2) {
            int j = gc * 32 + w * 8 + mi2 * 4 + quad;
            int gq = j >> 2, jr = j & 3;
#pragma unroll
            for (int ni = 0; ni < 2; ++ni) {
                int nl = ni * 16 + lm;
                OutsF[nl * 128 + ((gq ^ (nl & 7)) << 2) + jr] = fin[gc][mi2][ni];
            }
        }
    }
    __syncthreads();

    // coalesced store: 32 nodes x 128 floats
    {
        int row = tid >> 3;              // 0..31
        int cb = (tid & 7) * 16;         // 0..112
        int node = m0 + row;
        if (node < M) {
            float* dstp = out + (size_t)node * HID + cb;
#pragma unroll
            for (int i = 0; i < 4; ++i) {
                int gq = (cb >> 2) + i;
                *(float4*)(dstp + i * 4) = *(const float4*)&OutsF[row * 128 + ((gq ^ (row & 7)) << 2)];
            }
        }
    }
}

// ---------------------------------------------------------------------------

extern "C" void kernel_launch(void* const* d_in, const int* in_sizes, int n_in,
                              void* d_out, int out_size, void* d_ws, size_t ws_size,
                              hipStream_t stream) {
    const float* node_states = (const float*)d_in[0];
    const int*   edge_index  = (const int*)d_in[1];
    const int*   edge_type   = (const int*)d_in[2];
    const float* edge_W      = (const float*)d_in[3];
    const float* edge_b      = (const float*)d_in[4];
    const float* w_ih        = (const float*)d_in[5];
    const float* w_hh        = (const float*)d_in[6];
    const float* b_ih        = (const float*)d_in[7];
    const float* b_hh        = (const float*)d_in[8];

    const int M = in_sizes[0] / HID;      // 50000 nodes
    const int E = in_sizes[1] / 2;        // 625000 edges
    const int N4 = M * 4;                 // 200000 (dst,type) segments
    const int* src = edge_index;
    const int* dst = edge_index + E;

    // workspace layout (~79 MB)
    char* ws = (char*)d_ws;
    size_t off = 0;
    unsigned short* hbf   = (unsigned short*)(ws + off); off += (size_t)M * HID * 2;      // 12.8MB
    float*          bias4 = (float*)(ws + off);          off += (size_t)128 * 4 * 4;      // 2KB
    unsigned short* S     = (unsigned short*)(ws + off); off += (size_t)M * 512 * 2;      // 51.2MB
    unsigned short* Wcat  = (unsigned short*)(ws + off); off += (size_t)128 * 512 * 2;    // 128KB
    unsigned short* Wgru  = (unsigned short*)(ws + off); off += (size_t)512 * 256 * 2;    // 256KB
    float*          cnt4f = (float*)(ws + off);          off += (size_t)M * 4 * 4;        // 800KB
    int*            cnti  = (int*)(ws + off);            off += (size_t)N4 * 4;           // 800KB
    int*            ovfn  = (int*)(ws + off);            off += 16;                       // 16B
    int2*           ovf   = (int2*)(ws + off);           off += (size_t)OVF_MAX * 8;      // 512KB
    int*            csrF  = (int*)(ws + off);            off += (size_t)N4 * CAP * 4;     // 12.8MB

    const int total4 = M * HID / 4;
    const int nb_cvt  = (total4 + 255) / 256;    // 6250
    const int nb_fill = (E + 255) / 256;         // 2442

    // zero cnti + ovfn in one SDMA memset (contiguous)
    hipMemsetAsync(cnti, 0, (size_t)N4 * 4 + 16, stream);

    prep_fill_kernel<<<nb_cvt + 769 + nb_fill, 256, 0, stream>>>(
        node_states, hbf, edge_W, Wcat, w_ih, w_hh, Wgru, bias4, b_ih, b_hh,
        src, dst, edge_type, cnti, csrF, ovfn, ovf, total4, nb_cvt, E);

    gather_fixed_kernel<<<(M + 3) / 4, 256, 0, stream>>>(cnti, csrF, (const unsigned int*)hbf,
                                                         ovfn, ovf, (float4*)cnt4f,
                                                         (unsigned int*)S, M);

    agg_gru<<<(M + 31) / 32, 256, 0, stream>>>(S, Wcat, Wgru, hbf, (const float4*)cnt4f,
                                               edge_b, (const float4*)bias4, (float*)d_out, M);
}